// Round 2
// baseline (336.647 us; speedup 1.0000x reference)
//
#include <hip/hip_runtime.h>

using bf16x8  = __attribute__((ext_vector_type(8))) __bf16;
using f32x4   = __attribute__((ext_vector_type(4))) float;
using floatv4 = __attribute__((ext_vector_type(4))) float;
using ushortv4 = __attribute__((ext_vector_type(4))) unsigned short;
using ushortv8 = __attribute__((ext_vector_type(8))) unsigned short;

#define N_SEQ 4096
#define N_B   4
#define DIMK  1024
#define HS    128
#define ROWS  (N_B * N_SEQ)

__device__ __forceinline__ unsigned short f2bf(float f) {
    unsigned u = __builtin_bit_cast(unsigned, f);
    u += 0x7FFFu + ((u >> 16) & 1u);   // RNE
    return (unsigned short)(u >> 16);
}

// ---------------- projection: O = X @ W^T (per z: Wq, Wk, Wv) ----------------
// grid (128, 3), block 256. z<2 -> row-major bf16 out. z==2 -> V transposed [B][128][4096].
__global__ __launch_bounds__(256) void proj_kernel(
    const float* __restrict__ X,
    const float* __restrict__ Wq,
    const float* __restrict__ Wk,
    const float* __restrict__ Wv,
    unsigned short* __restrict__ Qb,
    unsigned short* __restrict__ Kb,
    unsigned short* __restrict__ Vt)
{
    const int z = blockIdx.y;
    const float* __restrict__ W = (z == 0) ? Wq : (z == 1) ? Wk : Wv;
    const int row0 = blockIdx.x * 128;
    __shared__ unsigned short smem[2 * 128 * 72];   // Xs[128][72], Ws[128][72]
    unsigned short* Xs = smem;
    unsigned short* Ws = smem + 128 * 72;
    const int tid  = threadIdx.x;
    const int wave = tid >> 6, lane = tid & 63;
    const int wm = wave >> 1, wn = wave & 1;
    const int lr = lane & 15, lg = lane >> 4;

    f32x4 acc[4][4] = {};

    for (int k0 = 0; k0 < DIMK; k0 += 64) {
        __syncthreads();
        #pragma unroll
        for (int i = 0; i < 8; ++i) {
            int idx = tid + i * 256;           // 0..2047 => 128 rows x 16 float4
            int r = idx >> 4;
            int c = (idx & 15) << 2;
            floatv4 xv = *reinterpret_cast<const floatv4*>(X + (size_t)(row0 + r) * DIMK + k0 + c);
            ushortv4 xh = { f2bf(xv.x), f2bf(xv.y), f2bf(xv.z), f2bf(xv.w) };
            *reinterpret_cast<ushortv4*>(&Xs[r * 72 + c]) = xh;
            floatv4 wv = *reinterpret_cast<const floatv4*>(W + (size_t)r * DIMK + k0 + c);
            ushortv4 wh = { f2bf(wv.x), f2bf(wv.y), f2bf(wv.z), f2bf(wv.w) };
            *reinterpret_cast<ushortv4*>(&Ws[r * 72 + c]) = wh;
        }
        __syncthreads();
        bf16x8 af[4][2], bfr[4][2];
        #pragma unroll
        for (int mi = 0; mi < 4; ++mi)
            #pragma unroll
            for (int kk = 0; kk < 2; ++kk)
                af[mi][kk] = *reinterpret_cast<const bf16x8*>(&Xs[(wm*64 + mi*16 + lr)*72 + kk*32 + lg*8]);
        #pragma unroll
        for (int ni = 0; ni < 4; ++ni)
            #pragma unroll
            for (int kk = 0; kk < 2; ++kk)
                bfr[ni][kk] = *reinterpret_cast<const bf16x8*>(&Ws[(wn*64 + ni*16 + lr)*72 + kk*32 + lg*8]);
        #pragma unroll
        for (int kk = 0; kk < 2; ++kk)
            #pragma unroll
            for (int mi = 0; mi < 4; ++mi)
                #pragma unroll
                for (int ni = 0; ni < 4; ++ni)
                    acc[mi][ni] = __builtin_amdgcn_mfma_f32_16x16x32_bf16(af[mi][kk], bfr[ni][kk], acc[mi][ni], 0, 0, 0);
    }

    if (z < 2) {
        unsigned short* O = (z == 0) ? Qb : Kb;
        #pragma unroll
        for (int mi = 0; mi < 4; ++mi) {
            int rowb = row0 + wm*64 + mi*16 + lg*4;
            #pragma unroll
            for (int ni = 0; ni < 4; ++ni) {
                int col = wn*64 + ni*16 + lr;
                #pragma unroll
                for (int r = 0; r < 4; ++r)
                    O[(size_t)(rowb + r) * HS + col] = f2bf(acc[mi][ni][r]);
            }
        }
    } else {
        // V: transpose through LDS, store Vt[b][d][n]
        __syncthreads();
        unsigned short* Cs = smem;   // [128][136] fits in 2*128*72
        #pragma unroll
        for (int mi = 0; mi < 4; ++mi)
            #pragma unroll
            for (int ni = 0; ni < 4; ++ni)
                #pragma unroll
                for (int r = 0; r < 4; ++r)
                    Cs[(wm*64 + mi*16 + lg*4 + r)*136 + wn*64 + ni*16 + lr] = f2bf(acc[mi][ni][r]);
        __syncthreads();
        const int b    = row0 >> 12;           // row0 / 4096
        const int nloc = row0 & (N_SEQ - 1);
        #pragma unroll
        for (int i = 0; i < 8; ++i) {
            int idx = tid + i * 256;           // 0..2047 => 128 d x 16 chunks
            int d  = idx & 127;
            int c8 = idx >> 7;
            ushortv8 v;
            #pragma unroll
            for (int j = 0; j < 8; ++j)
                v[j] = Cs[(c8*8 + j)*136 + d];
            *reinterpret_cast<ushortv8*>(Vt + (size_t)b * HS * N_SEQ + (size_t)d * N_SEQ + nloc + c8*8) = v;
        }
    }
}

// ---------------- flash attention, barrier-free, KV-split ----------------
// grid (256, S), block 256 = 4 waves. Each wave: 16 q-rows x (4096/S) kv.
// K/V read direct from global (L2-resident). P via per-wave private LDS.
__global__ __launch_bounds__(256) void attn_kernel(
    const unsigned short* __restrict__ Qb,
    const unsigned short* __restrict__ Kb,
    const unsigned short* __restrict__ Vt,
    float* __restrict__ part,    // [1024*S][16][128]
    float* __restrict__ plsum,   // [1024*S][16]
    float* __restrict__ outp,    // non-null (with S==1) => direct write
    int S)
{
    const int qblk  = blockIdx.x;      // [0,256)
    const int split = blockIdx.y;      // [0,S)
    const int tid  = threadIdx.x;
    const int wave = tid >> 6, lane = tid & 63;
    const int lr = lane & 15, lg = lane >> 4;
    const int qt   = qblk * 4 + wave;  // [0,1024) global q-tile (16 rows)
    const int b    = qt >> 8;
    const int row0 = (qt & 255) * 16;

    __shared__ unsigned short Ps[4][16 * 72];
    unsigned short* ps = Ps[wave];

    // Q fragments in registers for whole kernel
    bf16x8 qf[4];
    {
        const unsigned short* qp = Qb + ((size_t)b * N_SEQ + row0 + lr) * HS + lg * 8;
        #pragma unroll
        for (int kk = 0; kk < 4; ++kk)
            qf[kk] = *reinterpret_cast<const bf16x8*>(qp + kk * 32);
    }

    const int kvlen = N_SEQ / S;
    const int kv_begin = split * kvlen;
    const int nt = kvlen / 64;

    const unsigned short* kbase = Kb + (size_t)b * N_SEQ * HS + (size_t)lr * HS + lg * 8;
    const unsigned short* vbase = Vt + (size_t)b * HS * N_SEQ + (size_t)lr * N_SEQ + lg * 8;

    f32x4 ctx[8] = {};
    float lsum[4] = {0.f, 0.f, 0.f, 0.f};

    for (int t = 0; t < nt; ++t) {
        const int kv0 = kv_begin + t * 64;
        float psum[4] = {0.f, 0.f, 0.f, 0.f};
        #pragma unroll
        for (int ni = 0; ni < 4; ++ni) {
            const unsigned short* kp = kbase + (size_t)(kv0 + ni * 16) * HS;
            bf16x8 kf[4];
            #pragma unroll
            for (int kk = 0; kk < 4; ++kk)
                kf[kk] = *reinterpret_cast<const bf16x8*>(kp + kk * 32);
            f32x4 sv = {0.f, 0.f, 0.f, 0.f};
            #pragma unroll
            for (int kk = 0; kk < 4; ++kk)
                sv = __builtin_amdgcn_mfma_f32_16x16x32_bf16(qf[kk], kf[kk], sv, 0, 0, 0);
            #pragma unroll
            for (int r = 0; r < 4; ++r) {
                float pe = __expf(sv[r] * 0.03125f);
                psum[r] += pe;
                ps[(lg * 4 + r) * 72 + ni * 16 + lr] = f2bf(pe);
            }
        }
        #pragma unroll
        for (int r = 0; r < 4; ++r) {
            float v = psum[r];
            v += __shfl_xor(v, 1);
            v += __shfl_xor(v, 2);
            v += __shfl_xor(v, 4);
            v += __shfl_xor(v, 8);
            lsum[r] += v;
        }
        // ctx += P @ V  (P from own-wave LDS; V^T fragments direct from global)
        #pragma unroll
        for (int kk2 = 0; kk2 < 2; ++kk2) {
            bf16x8 pf = *reinterpret_cast<const bf16x8*>(&ps[lr * 72 + kk2 * 32 + lg * 8]);
            #pragma unroll
            for (int di = 0; di < 8; ++di) {
                bf16x8 vf = *reinterpret_cast<const bf16x8*>(
                    vbase + (size_t)(di * 16) * N_SEQ + kv0 + kk2 * 32);
                ctx[di] = __builtin_amdgcn_mfma_f32_16x16x32_bf16(pf, vf, ctx[di], 0, 0, 0);
            }
        }
    }

    if (outp != nullptr && S == 1) {
        const size_t orow = (size_t)b * N_SEQ + row0 + lg * 4;
        #pragma unroll
        for (int r = 0; r < 4; ++r) {
            float inv = 1.0f / lsum[r];
            #pragma unroll
            for (int di = 0; di < 8; ++di)
                outp[(orow + r) * HS + di * 16 + lr] = ctx[di][r] * inv;
        }
    } else {
        const size_t pidx = (size_t)qt * S + split;
        float* pp = part + pidx * (16 * 128);
        #pragma unroll
        for (int r = 0; r < 4; ++r) {
            #pragma unroll
            for (int di = 0; di < 8; ++di)
                pp[(lg * 4 + r) * 128 + di * 16 + lr] = ctx[di][r];
        }
        if (lr == 0) {
            #pragma unroll
            for (int r = 0; r < 4; ++r)
                plsum[pidx * 16 + lg * 4 + r] = lsum[r];
        }
    }
}

// combine KV-split partials: out[row][d] = sum_s ctx_s / sum_s lsum_s
__global__ __launch_bounds__(256) void reduce_kernel(
    const float* __restrict__ part,
    const float* __restrict__ plsum,
    float* __restrict__ out, int S)
{
    const int id = blockIdx.x * 256 + threadIdx.x;   // [0, 16384*128)
    const int d = id & 127;
    const int grow = id >> 7;
    const int qt = grow >> 4, r16 = grow & 15;
    float c = 0.f, l = 0.f;
    for (int s = 0; s < S; ++s) {
        c += part[((size_t)qt * S + s) * (16 * 128) + r16 * 128 + d];
        l += plsum[((size_t)qt * S + s) * 16 + r16];
    }
    out[id] = c / l;
}

extern "C" void kernel_launch(void* const* d_in, const int* in_sizes, int n_in,
                              void* d_out, int out_size, void* d_ws, size_t ws_size,
                              hipStream_t stream) {
    const float* x  = (const float*)d_in[0];
    const float* wq = (const float*)d_in[1];
    const float* wk = (const float*)d_in[2];
    const float* wv = (const float*)d_in[3];
    unsigned short* Qb = (unsigned short*)d_ws;                 // [16384][128] bf16
    unsigned short* Kb = Qb + (size_t)ROWS * HS;                // [16384][128] bf16
    unsigned short* Vt = Kb + (size_t)ROWS * HS;                // [4][128][4096] bf16
    const size_t base_bytes = (size_t)3 * ROWS * HS * 2;        // 12.58 MB
    const size_t per_split  = (size_t)1024 * 16 * 128 * 4 + (size_t)1024 * 16 * 4; // 8.45 MB

    int S; bool direct = false;
    if      (ws_size >= base_bytes + 4 * per_split) S = 4;
    else if (ws_size >= base_bytes + 2 * per_split) S = 2;
    else if (ws_size >= base_bytes + 1 * per_split) S = 1;
    else { S = 1; direct = true; }

    float* part  = (float*)((char*)d_ws + base_bytes);
    float* plsum = part + (size_t)1024 * S * 16 * 128;

    proj_kernel<<<dim3(128, 3), 256, 0, stream>>>(x, wq, wk, wv, Qb, Kb, Vt);
    attn_kernel<<<dim3(256, S), 256, 0, stream>>>(Qb, Kb, Vt,
                                                  direct ? (float*)d_ws : part,
                                                  direct ? (float*)d_ws : plsum,
                                                  direct ? (float*)d_out : nullptr, S);
    if (!direct)
        reduce_kernel<<<(ROWS * HS) / 256, 256, 0, stream>>>(part, plsum, (float*)d_out, S);
}

// Round 3
// 198.594 us; speedup vs baseline: 1.6952x; 1.6952x over previous
//
#include <hip/hip_runtime.h>

using bf16x8  = __attribute__((ext_vector_type(8))) __bf16;
using f32x4   = __attribute__((ext_vector_type(4))) float;
using floatv4 = __attribute__((ext_vector_type(4))) float;
using ushortv4 = __attribute__((ext_vector_type(4))) unsigned short;
using ushortv8 = __attribute__((ext_vector_type(8))) unsigned short;

#define N_SEQ 4096
#define N_B   4
#define DIMK  1024
#define HS    128
#define ROWS  (N_B * N_SEQ)
#define KVB   64

__device__ __forceinline__ unsigned short f2bf(float f) {
    unsigned u = __builtin_bit_cast(unsigned, f);
    u += 0x7FFFu + ((u >> 16) & 1u);   // RNE
    return (unsigned short)(u >> 16);
}

__device__ __forceinline__ void gload16(const unsigned short* g, unsigned short* l) {
    __builtin_amdgcn_global_load_lds(
        (const __attribute__((address_space(1))) unsigned int*)g,
        (__attribute__((address_space(3))) unsigned int*)l, 16, 0, 0);
}

// ---------------- projection: O = X @ W^T (per z: Wq, Wk, Wv) ----------------
__global__ __launch_bounds__(256) void proj_kernel(
    const float* __restrict__ X,
    const float* __restrict__ Wq,
    const float* __restrict__ Wk,
    const float* __restrict__ Wv,
    unsigned short* __restrict__ Qb,
    unsigned short* __restrict__ Kb,
    unsigned short* __restrict__ Vt)
{
    const int z = blockIdx.y;
    const float* __restrict__ W = (z == 0) ? Wq : (z == 1) ? Wk : Wv;
    const int row0 = blockIdx.x * 128;
    __shared__ unsigned short smem[2 * 128 * 72];
    unsigned short* Xs = smem;
    unsigned short* Ws = smem + 128 * 72;
    const int tid  = threadIdx.x;
    const int wave = tid >> 6, lane = tid & 63;
    const int wm = wave >> 1, wn = wave & 1;
    const int lr = lane & 15, lg = lane >> 4;

    f32x4 acc[4][4] = {};

    for (int k0 = 0; k0 < DIMK; k0 += 64) {
        __syncthreads();
        #pragma unroll
        for (int i = 0; i < 8; ++i) {
            int idx = tid + i * 256;
            int r = idx >> 4;
            int c = (idx & 15) << 2;
            floatv4 xv = *reinterpret_cast<const floatv4*>(X + (size_t)(row0 + r) * DIMK + k0 + c);
            ushortv4 xh = { f2bf(xv.x), f2bf(xv.y), f2bf(xv.z), f2bf(xv.w) };
            *reinterpret_cast<ushortv4*>(&Xs[r * 72 + c]) = xh;
            floatv4 wv = *reinterpret_cast<const floatv4*>(W + (size_t)r * DIMK + k0 + c);
            ushortv4 wh = { f2bf(wv.x), f2bf(wv.y), f2bf(wv.z), f2bf(wv.w) };
            *reinterpret_cast<ushortv4*>(&Ws[r * 72 + c]) = wh;
        }
        __syncthreads();
        bf16x8 af[4][2], bfr[4][2];
        #pragma unroll
        for (int mi = 0; mi < 4; ++mi)
            #pragma unroll
            for (int kk = 0; kk < 2; ++kk)
                af[mi][kk] = *reinterpret_cast<const bf16x8*>(&Xs[(wm*64 + mi*16 + lr)*72 + kk*32 + lg*8]);
        #pragma unroll
        for (int ni = 0; ni < 4; ++ni)
            #pragma unroll
            for (int kk = 0; kk < 2; ++kk)
                bfr[ni][kk] = *reinterpret_cast<const bf16x8*>(&Ws[(wn*64 + ni*16 + lr)*72 + kk*32 + lg*8]);
        #pragma unroll
        for (int kk = 0; kk < 2; ++kk)
            #pragma unroll
            for (int mi = 0; mi < 4; ++mi)
                #pragma unroll
                for (int ni = 0; ni < 4; ++ni)
                    acc[mi][ni] = __builtin_amdgcn_mfma_f32_16x16x32_bf16(af[mi][kk], bfr[ni][kk], acc[mi][ni], 0, 0, 0);
    }

    if (z < 2) {
        unsigned short* O = (z == 0) ? Qb : Kb;
        #pragma unroll
        for (int mi = 0; mi < 4; ++mi) {
            int rowb = row0 + wm*64 + mi*16 + lg*4;
            #pragma unroll
            for (int ni = 0; ni < 4; ++ni) {
                int col = wn*64 + ni*16 + lr;
                #pragma unroll
                for (int r = 0; r < 4; ++r)
                    O[(size_t)(rowb + r) * HS + col] = f2bf(acc[mi][ni][r]);
            }
        }
    } else {
        __syncthreads();
        unsigned short* Cs = smem;
        #pragma unroll
        for (int mi = 0; mi < 4; ++mi)
            #pragma unroll
            for (int ni = 0; ni < 4; ++ni)
                #pragma unroll
                for (int r = 0; r < 4; ++r)
                    Cs[(wm*64 + mi*16 + lg*4 + r)*136 + wn*64 + ni*16 + lr] = f2bf(acc[mi][ni][r]);
        __syncthreads();
        const int b    = row0 >> 12;
        const int nloc = row0 & (N_SEQ - 1);
        #pragma unroll
        for (int i = 0; i < 8; ++i) {
            int idx = tid + i * 256;
            int d  = idx & 127;
            int c8 = idx >> 7;
            ushortv8 v;
            #pragma unroll
            for (int j = 0; j < 8; ++j)
                v[j] = Cs[(c8*8 + j)*136 + d];
            *reinterpret_cast<ushortv8*>(Vt + (size_t)b * HS * N_SEQ + (size_t)d * N_SEQ + nloc + c8*8) = v;
        }
    }
}

// ---------------- flash attention: LDS-staged K/V (swizzled), KV-split ----------------
// grid (128, S), block 256 = 4 waves. Block: 128 q rows (32/wave) x kvlen.
__global__ __launch_bounds__(256) void attn_kernel(
    const unsigned short* __restrict__ Qb,
    const unsigned short* __restrict__ Kb,
    const unsigned short* __restrict__ Vt,
    float* __restrict__ part,    // [1024*S][16][128]
    float* __restrict__ plsum,   // [1024*S][16]
    int S)
{
    const int qblk  = blockIdx.x;      // [0,128)
    const int split = blockIdx.y;      // [0,S)
    const int tid  = threadIdx.x;
    const int wave = tid >> 6, lane = tid & 63;
    const int lr = lane & 15, lg = lane >> 4;
    const int b    = qblk >> 5;                       // 32 blocks of 128 rows per batch
    const int row0 = (qblk & 31) * 128 + wave * 32;   // wave's first q row in batch

    __shared__ unsigned short Ks[KVB * 128];   // [kv][d], slot^=(kv&7)
    __shared__ unsigned short Vs[128 * KVB];   // [d][kv], slot^=(d&7)
    __shared__ unsigned short Ps[4][32 * 72];  // per-wave P
    unsigned short* ps = Ps[wave];

    // Q fragments in registers: 2 sub-tiles x K=128
    bf16x8 qf[2][4];
    #pragma unroll
    for (int m = 0; m < 2; ++m) {
        const unsigned short* qp = Qb + ((size_t)b * N_SEQ + row0 + m*16 + lr) * HS + lg * 8;
        #pragma unroll
        for (int kk = 0; kk < 4; ++kk)
            qf[m][kk] = *reinterpret_cast<const bf16x8*>(qp + kk * 32);
    }

    const int kvlen = N_SEQ / S;
    const int nt = kvlen / KVB;
    const int kv_begin = split * kvlen;

    f32x4 ctx[2][8] = {};
    float lsum[2][4] = {};

    const unsigned short* Kbb = Kb + (size_t)b * N_SEQ * HS;
    const unsigned short* Vbb = Vt + (size_t)b * HS * N_SEQ;

    for (int t = 0; t < nt; ++t) {
        const int kv0 = kv_begin + t * KVB;
        // ---- stage K [64][128] : wave covers rows w*16..w*16+15, 4 instr ----
        #pragma unroll
        for (int i = 0; i < 4; ++i) {
            int r  = wave * 16 + i * 4 + (lane >> 4);
            int sp = (lane & 15) ^ (r & 7);
            gload16(Kbb + ((size_t)(kv0 + r)) * HS + sp * 8,
                    &Ks[(wave * 16 + i * 4) * 128]);
        }
        // ---- stage V^T [128][64] : wave covers d rows w*32..w*32+31, 4 instr ----
        #pragma unroll
        for (int i = 0; i < 4; ++i) {
            int r  = wave * 32 + i * 8 + (lane >> 3);
            int sp = (lane & 7) ^ (r & 7);
            gload16(Vbb + (size_t)r * N_SEQ + kv0 + sp * 8,
                    &Vs[(wave * 32 + i * 8) * KVB]);
        }
        __syncthreads();   // vmcnt(0): tiles resident

        // ---- S = Q K^T ; P = exp(S/32) -> per-wave LDS ----
        float psum[2][4] = {};
        #pragma unroll
        for (int ni = 0; ni < 4; ++ni) {
            bf16x8 kf[4];
            #pragma unroll
            for (int kk = 0; kk < 4; ++kk)
                kf[kk] = *reinterpret_cast<const bf16x8*>(
                    &Ks[(ni*16 + lr)*128 + (((kk*4 + lg) ^ (lr & 7)) * 8)]);
            #pragma unroll
            for (int m = 0; m < 2; ++m) {
                f32x4 sv = {0.f, 0.f, 0.f, 0.f};
                #pragma unroll
                for (int kk = 0; kk < 4; ++kk)
                    sv = __builtin_amdgcn_mfma_f32_16x16x32_bf16(qf[m][kk], kf[kk], sv, 0, 0, 0);
                #pragma unroll
                for (int r = 0; r < 4; ++r) {
                    float pe = __expf(sv[r] * 0.03125f);
                    psum[m][r] += pe;
                    ps[(m*16 + lg*4 + r)*72 + ni*16 + lr] = f2bf(pe);
                }
            }
        }
        #pragma unroll
        for (int m = 0; m < 2; ++m)
            #pragma unroll
            for (int r = 0; r < 4; ++r) {
                float v = psum[m][r];
                v += __shfl_xor(v, 1);
                v += __shfl_xor(v, 2);
                v += __shfl_xor(v, 4);
                v += __shfl_xor(v, 8);
                lsum[m][r] += v;
            }

        // ---- ctx += P @ V ----
        #pragma unroll
        for (int kk2 = 0; kk2 < 2; ++kk2) {
            bf16x8 pf[2];
            #pragma unroll
            for (int m = 0; m < 2; ++m)
                pf[m] = *reinterpret_cast<const bf16x8*>(&ps[(m*16 + lr)*72 + kk2*32 + lg*8]);
            #pragma unroll
            for (int di = 0; di < 8; ++di) {
                bf16x8 vf = *reinterpret_cast<const bf16x8*>(
                    &Vs[(di*16 + lr)*KVB + (((kk2*4 + lg) ^ (lr & 7)) * 8)]);
                #pragma unroll
                for (int m = 0; m < 2; ++m)
                    ctx[m][di] = __builtin_amdgcn_mfma_f32_16x16x32_bf16(pf[m], vf, ctx[m][di], 0, 0, 0);
            }
        }
        __syncthreads();   // all waves done reading Ks/Vs before next stage
    }

    // ---- write partials ----
    #pragma unroll
    for (int m = 0; m < 2; ++m) {
        const int qt = b * 256 + (qblk & 31) * 8 + wave * 2 + m;   // global 16-row tile
        const size_t pidx = (size_t)qt * S + split;
        float* pp = part + pidx * (16 * 128);
        #pragma unroll
        for (int r = 0; r < 4; ++r)
            #pragma unroll
            for (int di = 0; di < 8; ++di)
                pp[(lg*4 + r) * 128 + di*16 + lr] = ctx[m][di][r];
        if (lr == 0) {
            #pragma unroll
            for (int r = 0; r < 4; ++r)
                plsum[pidx * 16 + lg*4 + r] = lsum[m][r];
        }
    }
}

// combine KV-split partials: out = sum_s ctx_s / sum_s lsum_s  (float4 per thread)
__global__ __launch_bounds__(256) void reduce_kernel(
    const float* __restrict__ part,
    const float* __restrict__ plsum,
    float* __restrict__ out, int S)
{
    const int id = blockIdx.x * 256 + threadIdx.x;   // [0, 16384*128/4)
    const int d4 = (id & 31) * 4;
    const int grow = id >> 5;
    const int qt = grow >> 4, r16 = grow & 15;
    f32x4 c = {0.f, 0.f, 0.f, 0.f};
    float l = 0.f;
    for (int s = 0; s < S; ++s) {
        f32x4 pv = *reinterpret_cast<const f32x4*>(
            &part[(((size_t)qt * S + s) * 16 + r16) * 128 + d4]);
        c += pv;
        l += plsum[((size_t)qt * S + s) * 16 + r16];
    }
    float inv = 1.0f / l;
    f32x4 o = { c[0]*inv, c[1]*inv, c[2]*inv, c[3]*inv };
    *reinterpret_cast<f32x4*>(&out[(size_t)id * 4]) = o;
}

extern "C" void kernel_launch(void* const* d_in, const int* in_sizes, int n_in,
                              void* d_out, int out_size, void* d_ws, size_t ws_size,
                              hipStream_t stream) {
    const float* x  = (const float*)d_in[0];
    const float* wq = (const float*)d_in[1];
    const float* wk = (const float*)d_in[2];
    const float* wv = (const float*)d_in[3];
    unsigned short* Qb = (unsigned short*)d_ws;                 // [16384][128] bf16
    unsigned short* Kb = Qb + (size_t)ROWS * HS;                // [16384][128] bf16
    unsigned short* Vt = Kb + (size_t)ROWS * HS;                // [4][128][4096] bf16
    const size_t base_bytes = (size_t)3 * ROWS * HS * 2;        // 12.58 MB
    const size_t per_split  = (size_t)1024 * 16 * 128 * 4 + (size_t)1024 * 16 * 4; // 8.45 MB

    int S;
    if      (ws_size >= base_bytes + 8 * per_split) S = 8;
    else if (ws_size >= base_bytes + 4 * per_split) S = 4;
    else if (ws_size >= base_bytes + 2 * per_split) S = 2;
    else                                            S = 1;

    float* part  = (float*)((char*)d_ws + base_bytes);
    float* plsum = part + (size_t)1024 * S * 16 * 128;

    proj_kernel<<<dim3(128, 3), 256, 0, stream>>>(x, wq, wk, wv, Qb, Kb, Vt);
    attn_kernel<<<dim3(128, S), 256, 0, stream>>>(Qb, Kb, Vt, part, plsum, S);
    reduce_kernel<<<(ROWS * HS) / 1024, 256, 0, stream>>>(part, plsum, (float*)d_out, S);
}

// Round 4
// 100.814 us; speedup vs baseline: 3.3393x; 1.9699x over previous
//
#include <hip/hip_runtime.h>

using bf16x8   = __attribute__((ext_vector_type(8))) __bf16;
using f32x4    = __attribute__((ext_vector_type(4))) float;
using floatv4  = __attribute__((ext_vector_type(4))) float;
using ushortv8 = __attribute__((ext_vector_type(8))) unsigned short;

#define N_SEQ 4096
#define N_B   4
#define DIMK  1024
#define HS    128
#define ROWS  (N_B * N_SEQ)
#define KVB   32

__device__ __forceinline__ unsigned short f2bf(float f) {
    unsigned u = __builtin_bit_cast(unsigned, f);
    u += 0x7FFFu + ((u >> 16) & 1u);   // RNE
    return (unsigned short)(u >> 16);
}

__device__ __forceinline__ void gload16(const unsigned short* g, unsigned short* l) {
    __builtin_amdgcn_global_load_lds(
        (const __attribute__((address_space(1))) unsigned int*)g,
        (__attribute__((address_space(3))) unsigned int*)l, 16, 0, 0);
}

// ---------------- cast: X, Wq, Wk, Wv -> bf16 ----------------
// grid 8384 x 256 thr x 8 elems: blocks [0,8192) = X, [8192,8384) = W's
__global__ __launch_bounds__(256) void cast_kernel(
    const float* __restrict__ X,
    const float* __restrict__ Wq,
    const float* __restrict__ Wk,
    const float* __restrict__ Wv,
    unsigned short* __restrict__ Xb,
    unsigned short* __restrict__ Wb)
{
    const int blk = blockIdx.x;
    const float* src;
    unsigned short* dst;
    size_t off;
    if (blk < 8192) {
        src = X; dst = Xb; off = (size_t)blk * 2048;
    } else {
        int wblk = blk - 8192;              // 0..191, 64 blocks per W
        int z = wblk >> 6;
        src = (z == 0) ? Wq : (z == 1) ? Wk : Wv;
        dst = Wb + (size_t)z * (HS * DIMK);
        off = (size_t)(wblk & 63) * 2048;
    }
    size_t i = off + (size_t)threadIdx.x * 8;
    floatv4 a = *reinterpret_cast<const floatv4*>(src + i);
    floatv4 b = *reinterpret_cast<const floatv4*>(src + i + 4);
    ushortv8 o = { f2bf(a.x), f2bf(a.y), f2bf(a.z), f2bf(a.w),
                   f2bf(b.x), f2bf(b.y), f2bf(b.z), f2bf(b.w) };
    *reinterpret_cast<ushortv8*>(dst + i) = o;
}

// ---------------- projection: O = Xb @ Wz^T, double-buffered gload_lds ----------------
// grid (256, 3), block 256 = 4 waves. Tile 64 rows x 128 cols, BK=64.
// Wave wv owns cols wv*32..wv*32+31 (acc[4 mi][2 ni]).
__global__ __launch_bounds__(256, 3) void proj_kernel(
    const unsigned short* __restrict__ Xb,
    const unsigned short* __restrict__ Wb,
    unsigned short* __restrict__ Qb,
    unsigned short* __restrict__ Kb,
    unsigned short* __restrict__ Vt)
{
    const int z = blockIdx.y;
    const unsigned short* __restrict__ Wz = Wb + (size_t)z * (HS * DIMK);
    const int row0 = blockIdx.x * 64;
    __shared__ unsigned short smem[2 * 64 * 64 + 2 * 128 * 64];  // Xs[2], Ws[2]
    unsigned short* Xs0 = smem;
    unsigned short* Ws0 = smem + 2 * 64 * 64;
    const int tid = threadIdx.x;
    const int wv = tid >> 6, lane = tid & 63;
    const int lr = lane & 15, lg = lane >> 4;

    f32x4 acc[4][2] = {};

    auto stage = [&](int buf, int k0) {
        // X tile [64][64] bf16 = 8KB -> 8 gload16 (2/wave), rows in groups of 8
        #pragma unroll
        for (int i = 0; i < 2; ++i) {
            int g = wv * 2 + i;
            int r = g * 8 + (lane >> 3);
            int sp = (lane & 7) ^ (r & 7);
            gload16(Xb + (size_t)(row0 + r) * DIMK + k0 + sp * 8,
                    Xs0 + buf * (64 * 64) + g * 8 * 64);
        }
        // W tile [128][64] bf16 = 16KB -> 16 gload16 (4/wave)
        #pragma unroll
        for (int i = 0; i < 4; ++i) {
            int g = wv * 4 + i;
            int r = g * 8 + (lane >> 3);
            int sp = (lane & 7) ^ (r & 7);
            gload16(Wz + (size_t)r * DIMK + k0 + sp * 8,
                    Ws0 + buf * (128 * 64) + g * 8 * 64);
        }
    };

    stage(0, 0);
    __syncthreads();
    for (int ks = 0; ks < DIMK / 64; ++ks) {
        const int cur = ks & 1;
        if (ks < DIMK / 64 - 1) stage(cur ^ 1, (ks + 1) * 64);
        const unsigned short* Xc = Xs0 + cur * (64 * 64);
        const unsigned short* Wc = Ws0 + cur * (128 * 64);
        bf16x8 af[4][2], bfr[2][2];
        #pragma unroll
        for (int mi = 0; mi < 4; ++mi)
            #pragma unroll
            for (int kk = 0; kk < 2; ++kk)
                af[mi][kk] = *reinterpret_cast<const bf16x8*>(
                    &Xc[(mi * 16 + lr) * 64 + (((kk * 4 + lg) ^ (lr & 7)) * 8)]);
        #pragma unroll
        for (int ni = 0; ni < 2; ++ni)
            #pragma unroll
            for (int kk = 0; kk < 2; ++kk)
                bfr[ni][kk] = *reinterpret_cast<const bf16x8*>(
                    &Wc[(wv * 32 + ni * 16 + lr) * 64 + (((kk * 4 + lg) ^ (lr & 7)) * 8)]);
        #pragma unroll
        for (int kk = 0; kk < 2; ++kk)
            #pragma unroll
            for (int mi = 0; mi < 4; ++mi)
                #pragma unroll
                for (int ni = 0; ni < 2; ++ni)
                    acc[mi][ni] = __builtin_amdgcn_mfma_f32_16x16x32_bf16(
                        af[mi][kk], bfr[ni][kk], acc[mi][ni], 0, 0, 0);
        __syncthreads();
    }

    if (z < 2) {
        unsigned short* O = (z == 0) ? Qb : Kb;
        #pragma unroll
        for (int mi = 0; mi < 4; ++mi) {
            int rowb = row0 + mi * 16 + lg * 4;
            #pragma unroll
            for (int ni = 0; ni < 2; ++ni) {
                int col = wv * 32 + ni * 16 + lr;
                #pragma unroll
                for (int r = 0; r < 4; ++r)
                    O[(size_t)(rowb + r) * HS + col] = f2bf(acc[mi][ni][r]);
            }
        }
    } else {
        // V: transpose 64 x 128 through LDS, store Vt[b][d][n]
        unsigned short* Cs = smem;      // [64][132]
        #pragma unroll
        for (int mi = 0; mi < 4; ++mi)
            #pragma unroll
            for (int ni = 0; ni < 2; ++ni)
                #pragma unroll
                for (int r = 0; r < 4; ++r)
                    Cs[(mi * 16 + lg * 4 + r) * 132 + wv * 32 + ni * 16 + lr] = f2bf(acc[mi][ni][r]);
        __syncthreads();
        const int b  = row0 >> 12;
        const int n0 = row0 & (N_SEQ - 1);
        #pragma unroll
        for (int i = 0; i < 4; ++i) {
            int idx = tid + i * 256;        // 0..1023: 128 d x 8 chunks
            int d = idx >> 3, c8 = idx & 7;
            ushortv8 v;
            #pragma unroll
            for (int j = 0; j < 8; ++j)
                v[j] = Cs[(c8 * 8 + j) * 132 + d];
            *reinterpret_cast<ushortv8*>(Vt + (size_t)b * HS * N_SEQ + (size_t)d * N_SEQ + n0 + c8 * 8) = v;
        }
    }
}

// ---------------- flash attention: dbuf prefetch, KVB=32, ones-MFMA lsum ----------------
// grid (128, S), block 256 = 4 waves, 32 q-rows/wave.
__global__ __launch_bounds__(256, 2) void attn_kernel(
    const unsigned short* __restrict__ Qb,
    const unsigned short* __restrict__ Kb,
    const unsigned short* __restrict__ Vt,
    float* __restrict__ part,    // [1024][S][16][128]
    float* __restrict__ plsum,   // [1024][S][16]
    int S)
{
    const int qblk  = blockIdx.x;
    const int split = blockIdx.y;
    const int tid = threadIdx.x;
    const int wv = tid >> 6, lane = tid & 63;
    const int lr = lane & 15, lg = lane >> 4;
    const int b    = qblk >> 5;
    const int row0 = (qblk & 31) * 128 + wv * 32;

    __shared__ unsigned short Ks[2][KVB * 128];   // [kv][128], slot^=(kv&7)
    __shared__ unsigned short Vs[2][128 * KVB];   // [d][32], slot^=((d>>1)&3)
    __shared__ unsigned short Ps[4][32 * 40];     // per-wave P, stride 40
    unsigned short* ps = Ps[wv];

    bf16x8 qf[2][4];
    #pragma unroll
    for (int m = 0; m < 2; ++m) {
        const unsigned short* qp = Qb + ((size_t)b * N_SEQ + row0 + m * 16 + lr) * HS + lg * 8;
        #pragma unroll
        for (int kk = 0; kk < 4; ++kk)
            qf[m][kk] = *reinterpret_cast<const bf16x8*>(qp + kk * 32);
    }

    const int kvlen = N_SEQ / S;
    const int nt = kvlen / KVB;
    const int kv_begin = split * kvlen;
    const unsigned short* Kbb = Kb + (size_t)b * N_SEQ * HS;
    const unsigned short* Vbb = Vt + (size_t)b * HS * N_SEQ;

    auto stage = [&](int buf, int kv0) {
        #pragma unroll
        for (int i = 0; i < 2; ++i) {          // K [32][128]: 8 groups of 4 rows
            int g = wv * 2 + i;
            int r = g * 4 + (lane >> 4);
            int sp = (lane & 15) ^ (r & 7);
            gload16(Kbb + (size_t)(kv0 + r) * HS + sp * 8, &Ks[buf][g * 4 * 128]);
        }
        #pragma unroll
        for (int i = 0; i < 2; ++i) {          // V^T [128][32]: 8 groups of 16 rows
            int g = wv * 2 + i;
            int r = g * 16 + (lane >> 2);
            int sp = (lane & 3) ^ ((r >> 1) & 3);
            gload16(Vbb + (size_t)r * N_SEQ + kv0 + sp * 8, &Vs[buf][g * 16 * KVB]);
        }
    };

    f32x4 ctx[2][8] = {};
    f32x4 lacc[2] = {};
    const ushortv8 ones_u = {0x3F80,0x3F80,0x3F80,0x3F80,0x3F80,0x3F80,0x3F80,0x3F80};
    const bf16x8 onesf = __builtin_bit_cast(bf16x8, ones_u);
    const float CEXP = 0.045084220027780106f;   // log2(e)/32

    stage(0, kv_begin);
    __syncthreads();
    for (int t = 0; t < nt; ++t) {
        const int cur = t & 1;
        if (t + 1 < nt) stage(cur ^ 1, kv_begin + (t + 1) * KVB);

        // S = Q K^T ; P = exp2(S*CEXP) -> per-wave LDS
        #pragma unroll
        for (int ni = 0; ni < 2; ++ni) {
            bf16x8 kf[4];
            #pragma unroll
            for (int kk = 0; kk < 4; ++kk)
                kf[kk] = *reinterpret_cast<const bf16x8*>(
                    &Ks[cur][(ni * 16 + lr) * 128 + (((kk * 4 + lg) ^ (lr & 7)) * 8)]);
            #pragma unroll
            for (int m = 0; m < 2; ++m) {
                f32x4 sv = {0.f, 0.f, 0.f, 0.f};
                #pragma unroll
                for (int kk = 0; kk < 4; ++kk)
                    sv = __builtin_amdgcn_mfma_f32_16x16x32_bf16(qf[m][kk], kf[kk], sv, 0, 0, 0);
                #pragma unroll
                for (int r = 0; r < 4; ++r) {
                    float pe = exp2f(sv[r] * CEXP);
                    ps[(m * 16 + lg * 4 + r) * 40 + ni * 16 + lr] = f2bf(pe);
                }
            }
        }

        // ctx += P @ V ; lsum += P @ ones (free row-sum in matching layout)
        bf16x8 pf0 = *reinterpret_cast<const bf16x8*>(&ps[lr * 40 + lg * 8]);
        bf16x8 pf1 = *reinterpret_cast<const bf16x8*>(&ps[(16 + lr) * 40 + lg * 8]);
        lacc[0] = __builtin_amdgcn_mfma_f32_16x16x32_bf16(pf0, onesf, lacc[0], 0, 0, 0);
        lacc[1] = __builtin_amdgcn_mfma_f32_16x16x32_bf16(pf1, onesf, lacc[1], 0, 0, 0);
        #pragma unroll
        for (int di = 0; di < 8; ++di) {
            bf16x8 vf = *reinterpret_cast<const bf16x8*>(
                &Vs[cur][(di * 16 + lr) * KVB + ((lg ^ ((lr >> 1) & 3)) * 8)]);
            ctx[0][di] = __builtin_amdgcn_mfma_f32_16x16x32_bf16(pf0, vf, ctx[0][di], 0, 0, 0);
            ctx[1][di] = __builtin_amdgcn_mfma_f32_16x16x32_bf16(pf1, vf, ctx[1][di], 0, 0, 0);
        }
        __syncthreads();
    }

    // write partials
    #pragma unroll
    for (int m = 0; m < 2; ++m) {
        const int qt = b * 256 + (qblk & 31) * 8 + wv * 2 + m;
        const size_t pidx = (size_t)qt * S + split;
        float* pp = part + pidx * (16 * 128);
        #pragma unroll
        for (int r = 0; r < 4; ++r)
            #pragma unroll
            for (int di = 0; di < 8; ++di)
                pp[(lg * 4 + r) * 128 + di * 16 + lr] = ctx[m][di][r];
        if (lr == 0) {
            #pragma unroll
            for (int r = 0; r < 4; ++r)
                plsum[pidx * 16 + lg * 4 + r] = lacc[m][r];
        }
    }
}

// combine KV-split partials
__global__ __launch_bounds__(256) void reduce_kernel(
    const float* __restrict__ part,
    const float* __restrict__ plsum,
    float* __restrict__ out, int S)
{
    const int id = blockIdx.x * 256 + threadIdx.x;   // [0, 16384*128/4)
    const int d4 = (id & 31) * 4;
    const int grow = id >> 5;
    const int qt = grow >> 4, r16 = grow & 15;
    f32x4 c = {0.f, 0.f, 0.f, 0.f};
    float l = 0.f;
    for (int s = 0; s < S; ++s) {
        f32x4 pv = *reinterpret_cast<const f32x4*>(
            &part[(((size_t)qt * S + s) * 16 + r16) * 128 + d4]);
        c += pv;
        l += plsum[((size_t)qt * S + s) * 16 + r16];
    }
    float inv = 1.0f / l;
    f32x4 o = { c[0]*inv, c[1]*inv, c[2]*inv, c[3]*inv };
    *reinterpret_cast<f32x4*>(&out[(size_t)id * 4]) = o;
}

extern "C" void kernel_launch(void* const* d_in, const int* in_sizes, int n_in,
                              void* d_out, int out_size, void* d_ws, size_t ws_size,
                              hipStream_t stream) {
    const float* x  = (const float*)d_in[0];
    const float* wq = (const float*)d_in[1];
    const float* wk = (const float*)d_in[2];
    const float* wv = (const float*)d_in[3];

    // ws layout: Xb | Wb | Qb | Kb | Vt | plsum ; part aliases Xb (dead after proj)
    unsigned short* Xb = (unsigned short*)d_ws;                 // 16.8M elems (33.55 MB)
    unsigned short* Wb = Xb + (size_t)ROWS * DIMK;              // 393K elems
    unsigned short* Qb = Wb + (size_t)3 * HS * DIMK;            // 2.1M elems
    unsigned short* Kb = Qb + (size_t)ROWS * HS;
    unsigned short* Vt = Kb + (size_t)ROWS * HS;
    float* plsum = (float*)(Vt + (size_t)N_B * HS * N_SEQ);
    float* part  = (float*)d_ws;                                // alias Xb: S*8.39MB <= 33.55MB

    const size_t base = ((size_t)ROWS * DIMK + 3 * HS * DIMK + 3 * (size_t)ROWS * HS) * 2;
    int S;
    if      (ws_size >= base + 4 * (size_t)1024 * 16 * 4) S = 4;
    else if (ws_size >= base + 2 * (size_t)1024 * 16 * 4) S = 2;
    else                                                  S = 1;

    cast_kernel<<<8192 + 192, 256, 0, stream>>>(x, wq, wk, wv, Xb, Wb);
    proj_kernel<<<dim3(256, 3), 256, 0, stream>>>(Xb, Wb, Qb, Kb, Vt);
    attn_kernel<<<dim3(128, S), 256, 0, stream>>>(Qb, Kb, Vt, part, plsum, S);
    reduce_kernel<<<(ROWS * HS) / 1024, 256, 0, stream>>>(part, plsum, (float*)d_out, S);
}

// Round 5
// 94.062 us; speedup vs baseline: 3.5790x; 1.0718x over previous
//
#include <hip/hip_runtime.h>

using bf16x8   = __attribute__((ext_vector_type(8))) __bf16;
using f32x4    = __attribute__((ext_vector_type(4))) float;
using f32x16   = __attribute__((ext_vector_type(16))) float;
using floatv4  = __attribute__((ext_vector_type(4))) float;
using ushortv4 = __attribute__((ext_vector_type(4))) unsigned short;
using ushortv8 = __attribute__((ext_vector_type(8))) unsigned short;
using uintv4   = __attribute__((ext_vector_type(4))) unsigned int;

#define N_SEQ 4096
#define N_B   4
#define DIMK  1024
#define HS    128
#define ROWS  (N_B * N_SEQ)
#define KVB   32

__device__ __forceinline__ unsigned short f2bf(float f) {
    unsigned u = __builtin_bit_cast(unsigned, f);
    u += 0x7FFFu + ((u >> 16) & 1u);   // RNE
    return (unsigned short)(u >> 16);
}

__device__ __forceinline__ unsigned cvtpk(float lo, float hi) {
    unsigned r;
    asm("v_cvt_pk_bf16_f32 %0, %1, %2" : "=v"(r) : "v"(lo), "v"(hi));
    return r;
}

__device__ __forceinline__ void gload16(const unsigned short* g, unsigned short* l) {
    __builtin_amdgcn_global_load_lds(
        (const __attribute__((address_space(1))) unsigned int*)g,
        (__attribute__((address_space(3))) unsigned int*)l, 16, 0, 0);
}

// ---------------- cast: X, Wq, Wk, Wv -> bf16 ----------------
__global__ __launch_bounds__(256) void cast_kernel(
    const float* __restrict__ X,
    const float* __restrict__ Wq,
    const float* __restrict__ Wk,
    const float* __restrict__ Wv,
    unsigned short* __restrict__ Xb,
    unsigned short* __restrict__ Wb)
{
    const int blk = blockIdx.x;
    const float* src;
    unsigned short* dst;
    size_t off;
    if (blk < 8192) {
        src = X; dst = Xb; off = (size_t)blk * 2048;
    } else {
        int wblk = blk - 8192;
        int z = wblk >> 6;
        src = (z == 0) ? Wq : (z == 1) ? Wk : Wv;
        dst = Wb + (size_t)z * (HS * DIMK);
        off = (size_t)(wblk & 63) * 2048;
    }
    size_t i = off + (size_t)threadIdx.x * 8;
    floatv4 a = *reinterpret_cast<const floatv4*>(src + i);
    floatv4 b = *reinterpret_cast<const floatv4*>(src + i + 4);
    ushortv8 o = { f2bf(a.x), f2bf(a.y), f2bf(a.z), f2bf(a.w),
                   f2bf(b.x), f2bf(b.y), f2bf(b.z), f2bf(b.w) };
    *reinterpret_cast<ushortv8*>(dst + i) = o;
}

// ---------------- projection: O = Xb @ Wz^T, double-buffered gload_lds ----------------
__global__ __launch_bounds__(256, 3) void proj_kernel(
    const unsigned short* __restrict__ Xb,
    const unsigned short* __restrict__ Wb,
    unsigned short* __restrict__ Qb,
    unsigned short* __restrict__ Kb,
    unsigned short* __restrict__ Vt)
{
    const int z = blockIdx.y;
    const unsigned short* __restrict__ Wz = Wb + (size_t)z * (HS * DIMK);
    const int row0 = blockIdx.x * 64;
    __shared__ unsigned short smem[2 * 64 * 64 + 2 * 128 * 64];
    unsigned short* Xs0 = smem;
    unsigned short* Ws0 = smem + 2 * 64 * 64;
    const int tid = threadIdx.x;
    const int wv = tid >> 6, lane = tid & 63;
    const int lr = lane & 15, lg = lane >> 4;

    f32x4 acc[4][2] = {};

    auto stage = [&](int buf, int k0) {
        #pragma unroll
        for (int i = 0; i < 2; ++i) {
            int g = wv * 2 + i;
            int r = g * 8 + (lane >> 3);
            int sp = (lane & 7) ^ (r & 7);
            gload16(Xb + (size_t)(row0 + r) * DIMK + k0 + sp * 8,
                    Xs0 + buf * (64 * 64) + g * 8 * 64);
        }
        #pragma unroll
        for (int i = 0; i < 4; ++i) {
            int g = wv * 4 + i;
            int r = g * 8 + (lane >> 3);
            int sp = (lane & 7) ^ (r & 7);
            gload16(Wz + (size_t)r * DIMK + k0 + sp * 8,
                    Ws0 + buf * (128 * 64) + g * 8 * 64);
        }
    };

    stage(0, 0);
    __syncthreads();
    for (int ks = 0; ks < DIMK / 64; ++ks) {
        const int cur = ks & 1;
        if (ks < DIMK / 64 - 1) stage(cur ^ 1, (ks + 1) * 64);
        const unsigned short* Xc = Xs0 + cur * (64 * 64);
        const unsigned short* Wc = Ws0 + cur * (128 * 64);
        bf16x8 af[4][2], bfr[2][2];
        #pragma unroll
        for (int mi = 0; mi < 4; ++mi)
            #pragma unroll
            for (int kk = 0; kk < 2; ++kk)
                af[mi][kk] = *reinterpret_cast<const bf16x8*>(
                    &Xc[(mi * 16 + lr) * 64 + (((kk * 4 + lg) ^ (lr & 7)) * 8)]);
        #pragma unroll
        for (int ni = 0; ni < 2; ++ni)
            #pragma unroll
            for (int kk = 0; kk < 2; ++kk)
                bfr[ni][kk] = *reinterpret_cast<const bf16x8*>(
                    &Wc[(wv * 32 + ni * 16 + lr) * 64 + (((kk * 4 + lg) ^ (lr & 7)) * 8)]);
        #pragma unroll
        for (int kk = 0; kk < 2; ++kk)
            #pragma unroll
            for (int mi = 0; mi < 4; ++mi)
                #pragma unroll
                for (int ni = 0; ni < 2; ++ni)
                    acc[mi][ni] = __builtin_amdgcn_mfma_f32_16x16x32_bf16(
                        af[mi][kk], bfr[ni][kk], acc[mi][ni], 0, 0, 0);
        __syncthreads();
    }

    if (z < 2) {
        unsigned short* O = (z == 0) ? Qb : Kb;
        #pragma unroll
        for (int mi = 0; mi < 4; ++mi) {
            int rowb = row0 + mi * 16 + lg * 4;
            #pragma unroll
            for (int ni = 0; ni < 2; ++ni) {
                int col = wv * 32 + ni * 16 + lr;
                #pragma unroll
                for (int r = 0; r < 4; ++r)
                    O[(size_t)(rowb + r) * HS + col] = f2bf(acc[mi][ni][r]);
            }
        }
    } else {
        unsigned short* Cs = smem;      // [64][132]
        #pragma unroll
        for (int mi = 0; mi < 4; ++mi)
            #pragma unroll
            for (int ni = 0; ni < 2; ++ni)
                #pragma unroll
                for (int r = 0; r < 4; ++r)
                    Cs[(mi * 16 + lg * 4 + r) * 132 + wv * 32 + ni * 16 + lr] = f2bf(acc[mi][ni][r]);
        __syncthreads();
        const int b  = row0 >> 12;
        const int n0 = row0 & (N_SEQ - 1);
        #pragma unroll
        for (int i = 0; i < 4; ++i) {
            int idx = tid + i * 256;
            int d = idx >> 3, c8 = idx & 7;
            ushortv8 v;
            #pragma unroll
            for (int j = 0; j < 8; ++j)
                v[j] = Cs[(c8 * 8 + j) * 132 + d];
            *reinterpret_cast<ushortv8*>(Vt + (size_t)b * HS * N_SEQ + (size_t)d * N_SEQ + n0 + c8 * 8) = v;
        }
    }
}

// ---------------- flash attention: 32x32 swapped QK^T, in-register softmax ----------------
// grid (128, S), block 256 = 4 waves, 32 q-rows/wave. LDS = K/V dbuf only (32 KB).
__global__ __launch_bounds__(256, 3) void attn_kernel(
    const unsigned short* __restrict__ Qb,
    const unsigned short* __restrict__ Kb,
    const unsigned short* __restrict__ Vt,
    unsigned short* __restrict__ part,   // [512][S][32][128] bf16
    float* __restrict__ plsum,           // [512][S][32]
    int S)
{
    const int qblk  = blockIdx.x;      // [0,128)
    const int split = blockIdx.y;      // [0,S)
    const int tid = threadIdx.x;
    const int wv = tid >> 6, lane = tid & 63;
    const int l31 = lane & 31, h = lane >> 5;
    const int b    = qblk >> 5;
    const int row0 = (qblk & 31) * 128 + wv * 32;

    __shared__ unsigned short Ks[2][KVB * 128];   // [kv][hd], slot16 ^= (kv&7)
    __shared__ unsigned short Vs[2][128 * KVB];   // [d][kv],  slot4  ^= ((d>>1)&3)

    // Q as B-fragment: lane l holds Q[q=row0+l31][hd = kk*16 + h*8 + j]
    bf16x8 qf[8];
    {
        const unsigned short* qp = Qb + ((size_t)b * N_SEQ + row0 + l31) * HS + h * 8;
        #pragma unroll
        for (int kk = 0; kk < 8; ++kk)
            qf[kk] = *reinterpret_cast<const bf16x8*>(qp + kk * 16);
    }

    const int kvlen = N_SEQ / S;
    const int nt = kvlen / KVB;
    const int kv_begin = split * kvlen;
    const unsigned short* Kbb = Kb + (size_t)b * N_SEQ * HS;
    const unsigned short* Vbb = Vt + (size_t)b * HS * N_SEQ;

    auto stage = [&](int buf, int kv0) {
        #pragma unroll
        for (int i = 0; i < 2; ++i) {          // K [32][128]
            int g = wv * 2 + i;
            int r = g * 4 + (lane >> 4);
            int sp = (lane & 15) ^ (r & 7);
            gload16(Kbb + (size_t)(kv0 + r) * HS + sp * 8, &Ks[buf][g * 4 * 128]);
        }
        #pragma unroll
        for (int i = 0; i < 2; ++i) {          // V^T [128][32]
            int g = wv * 2 + i;
            int r = g * 16 + (lane >> 2);
            int sp = (lane & 3) ^ ((r >> 1) & 3);
            gload16(Vbb + (size_t)r * N_SEQ + kv0 + sp * 8, &Vs[buf][g * 16 * KVB]);
        }
    };

    f32x16 ctx[4] = {};                        // ctx[dt]: rows q(r,h), col d=dt*32+l31
    f32x16 lacc = {};                          // lsum replicated, same row map as ctx
    const ushortv8 ones_u = {0x3F80,0x3F80,0x3F80,0x3F80,0x3F80,0x3F80,0x3F80,0x3F80};
    const bf16x8 onesf = __builtin_bit_cast(bf16x8, ones_u);
    const float CEXP = 0.045084220027780106f;  // log2(e)/32

    stage(0, kv_begin);
    __syncthreads();
    for (int t = 0; t < nt; ++t) {
        const int cur = t & 1;
        if (t + 1 < nt) stage(cur ^ 1, kv_begin + (t + 1) * KVB);

        // S^T = K Q^T (swapped): lane holds S^T[kv(r,h)][q=l31]
        f32x16 st = {};
        #pragma unroll
        for (int kk = 0; kk < 8; ++kk) {
            bf16x8 kf = *reinterpret_cast<const bf16x8*>(
                &Ks[cur][l31 * 128 + (((kk * 2 + h) ^ (l31 & 7)) * 8)]);
            st = __builtin_amdgcn_mfma_f32_32x32x16_bf16(kf, qf[kk], st, 0, 0, 0);
        }

        // P = exp2(S*CEXP) in registers; repack to PV A-fragments via cvt_pk + permlane32_swap
        float p[16];
        #pragma unroll
        for (int r = 0; r < 16; ++r)
            p[r] = exp2f(st[r] * CEXP);

        bf16x8 pf[2];
        #pragma unroll
        for (int half = 0; half < 2; ++half) {
            unsigned a = cvtpk(p[half*8 + 0], p[half*8 + 1]);
            unsigned bq = cvtpk(p[half*8 + 2], p[half*8 + 3]);
            unsigned c = cvtpk(p[half*8 + 4], p[half*8 + 5]);
            unsigned d = cvtpk(p[half*8 + 6], p[half*8 + 7]);
            asm("v_permlane32_swap_b32 %0, %1" : "+v"(a), "+v"(c));
            asm("v_permlane32_swap_b32 %0, %1" : "+v"(bq), "+v"(d));
            uintv4 w = { a, bq, c, d };
            pf[half] = __builtin_bit_cast(bf16x8, w);
        }

        lacc = __builtin_amdgcn_mfma_f32_32x32x16_bf16(pf[0], onesf, lacc, 0, 0, 0);
        lacc = __builtin_amdgcn_mfma_f32_32x32x16_bf16(pf[1], onesf, lacc, 0, 0, 0);

        // ctx += P @ V : B-frag from Vs rows d=dt*32+l31, kv-slot = half*2+h
        #pragma unroll
        for (int dt = 0; dt < 4; ++dt) {
            int d = dt * 32 + l31;
            bf16x8 vf0 = *reinterpret_cast<const bf16x8*>(
                &Vs[cur][d * KVB + (((0 + h) ^ ((d >> 1) & 3)) * 8)]);
            ctx[dt] = __builtin_amdgcn_mfma_f32_32x32x16_bf16(pf[0], vf0, ctx[dt], 0, 0, 0);
            bf16x8 vf1 = *reinterpret_cast<const bf16x8*>(
                &Vs[cur][d * KVB + (((2 + h) ^ ((d >> 1) & 3)) * 8)]);
            ctx[dt] = __builtin_amdgcn_mfma_f32_32x32x16_bf16(pf[1], vf1, ctx[dt], 0, 0, 0);
        }
        __syncthreads();
    }

    // ---- write bf16 partials ----
    const int qt = qblk * 4 + wv;              // [0,512) 32-row tile
    unsigned short* pp = part + ((size_t)qt * S + split) * (32 * 128);
    #pragma unroll
    for (int rp = 0; rp < 4; ++rp)
        #pragma unroll
        for (int rq = 0; rq < 4; ++rq) {
            const int r = rp * 4 + rq;
            const int q = rq + 8 * rp + 4 * h;
            #pragma unroll
            for (int dt = 0; dt < 4; ++dt)
                pp[q * 128 + dt * 32 + l31] = (unsigned short)(cvtpk(ctx[dt][r], ctx[dt][r]) & 0xFFFFu);
        }
    if (l31 == 0) {
        float* pl = plsum + ((size_t)qt * S + split) * 32;
        #pragma unroll
        for (int rp = 0; rp < 4; ++rp)
            #pragma unroll
            for (int rq = 0; rq < 4; ++rq)
                pl[rq + 8 * rp + 4 * h] = lacc[rp * 4 + rq];
    }
}

// combine KV-split partials: out = (sum_s part_s) / (sum_s lsum_s)
__global__ __launch_bounds__(256) void reduce_kernel(
    const unsigned short* __restrict__ part,
    const float* __restrict__ plsum,
    float* __restrict__ out, int S)
{
    const int id = blockIdx.x * 256 + threadIdx.x;   // [0, 16384*128/4)
    const int d4 = (id & 31) * 4;
    const int grow = id >> 5;                        // global q row
    const int qt = grow >> 5, q = grow & 31;
    f32x4 c = {0.f, 0.f, 0.f, 0.f};
    float l = 0.f;
    for (int s = 0; s < S; ++s) {
        ushortv4 pv = *reinterpret_cast<const ushortv4*>(
            &part[(((size_t)qt * S + s) * 32 + q) * 128 + d4]);
        #pragma unroll
        for (int j = 0; j < 4; ++j)
            c[j] += __builtin_bit_cast(float, (unsigned)pv[j] << 16);
        l += plsum[((size_t)qt * S + s) * 32 + q];
    }
    float inv = 1.0f / l;
    f32x4 o = { c[0]*inv, c[1]*inv, c[2]*inv, c[3]*inv };
    *reinterpret_cast<f32x4*>(&out[(size_t)grow * 128 + d4]) = o;
}

extern "C" void kernel_launch(void* const* d_in, const int* in_sizes, int n_in,
                              void* d_out, int out_size, void* d_ws, size_t ws_size,
                              hipStream_t stream) {
    const float* x  = (const float*)d_in[0];
    const float* wq = (const float*)d_in[1];
    const float* wk = (const float*)d_in[2];
    const float* wv = (const float*)d_in[3];

    // ws layout: Xb | Wb | Qb | Kb | Vt | plsum ; bf16 part aliases Xb (dead after proj)
    unsigned short* Xb = (unsigned short*)d_ws;                 // 33.55 MB
    unsigned short* Wb = Xb + (size_t)ROWS * DIMK;
    unsigned short* Qb = Wb + (size_t)3 * HS * DIMK;
    unsigned short* Kb = Qb + (size_t)ROWS * HS;
    unsigned short* Vt = Kb + (size_t)ROWS * HS;
    float* plsum = (float*)(Vt + (size_t)N_B * HS * N_SEQ);
    unsigned short* part = (unsigned short*)d_ws;               // S*4.19MB <= 33.55MB for S<=8

    const size_t base = ((size_t)ROWS * DIMK + 3 * HS * DIMK + 3 * (size_t)ROWS * HS) * 2;
    int S;
    if      (ws_size >= base + 8 * (size_t)512 * 32 * 4) S = 8;
    else if (ws_size >= base + 4 * (size_t)512 * 32 * 4) S = 4;
    else if (ws_size >= base + 2 * (size_t)512 * 32 * 4) S = 2;
    else                                                 S = 1;

    cast_kernel<<<8192 + 192, 256, 0, stream>>>(x, wq, wk, wv, Xb, Wb);
    proj_kernel<<<dim3(256, 3), 256, 0, stream>>>(Xb, Wb, Qb, Kb, Vt);
    attn_kernel<<<dim3(128, S), 256, 0, stream>>>(Qb, Kb, Vt, part, plsum, S);
    reduce_kernel<<<(ROWS * HS) / 1024, 256, 0, stream>>>(part, plsum, (float*)d_out, S);
}

// Round 6
// 83.575 us; speedup vs baseline: 4.0281x; 1.1255x over previous
//
#include <hip/hip_runtime.h>

using bf16x8   = __attribute__((ext_vector_type(8))) __bf16;
using f32x4    = __attribute__((ext_vector_type(4))) float;
using f32x16   = __attribute__((ext_vector_type(16))) float;
using floatv4  = __attribute__((ext_vector_type(4))) float;
using ushortv4 = __attribute__((ext_vector_type(4))) unsigned short;
using ushortv8 = __attribute__((ext_vector_type(8))) unsigned short;
using uintv4   = __attribute__((ext_vector_type(4))) unsigned int;

#define N_SEQ 4096
#define N_B   4
#define DIMK  1024
#define HS    128
#define ROWS  (N_B * N_SEQ)
#define KVB   32
#define TT    (N_SEQ / KVB)   // 128 kv tiles

__device__ __forceinline__ unsigned short f2bf(float f) {
    unsigned u = __builtin_bit_cast(unsigned, f);
    u += 0x7FFFu + ((u >> 16) & 1u);   // RNE
    return (unsigned short)(u >> 16);
}

__device__ __forceinline__ unsigned cvtpk(float lo, float hi) {
    unsigned r;
    asm("v_cvt_pk_bf16_f32 %0, %1, %2" : "=v"(r) : "v"(lo), "v"(hi));
    return r;
}

__device__ __forceinline__ void gload16(const unsigned short* g, unsigned short* l) {
    __builtin_amdgcn_global_load_lds(
        (const __attribute__((address_space(1))) unsigned int*)g,
        (__attribute__((address_space(3))) unsigned int*)l, 16, 0, 0);
}

// ---------------- cast: X, Wq, Wk, Wv -> bf16 ----------------
__global__ __launch_bounds__(256) void cast_kernel(
    const float* __restrict__ X,
    const float* __restrict__ Wq,
    const float* __restrict__ Wk,
    const float* __restrict__ Wv,
    unsigned short* __restrict__ Xb,
    unsigned short* __restrict__ Wb)
{
    const int blk = blockIdx.x;
    const float* src;
    unsigned short* dst;
    size_t off;
    if (blk < 8192) {
        src = X; dst = Xb; off = (size_t)blk * 2048;
    } else {
        int wblk = blk - 8192;
        int z = wblk >> 6;
        src = (z == 0) ? Wq : (z == 1) ? Wk : Wv;
        dst = Wb + (size_t)z * (HS * DIMK);
        off = (size_t)(wblk & 63) * 2048;
    }
    size_t i = off + (size_t)threadIdx.x * 8;
    floatv4 a = *reinterpret_cast<const floatv4*>(src + i);
    floatv4 b = *reinterpret_cast<const floatv4*>(src + i + 4);
    ushortv8 o = { f2bf(a.x), f2bf(a.y), f2bf(a.z), f2bf(a.w),
                   f2bf(b.x), f2bf(b.y), f2bf(b.z), f2bf(b.w) };
    *reinterpret_cast<ushortv8*>(dst + i) = o;
}

// ---------------- projection: O = Xb @ Wz^T, double-buffered gload_lds ----------------
// Q output is pre-scaled by log2(e)/32 so attention can use exp2 directly.
__global__ __launch_bounds__(256, 3) void proj_kernel(
    const unsigned short* __restrict__ Xb,
    const unsigned short* __restrict__ Wb,
    unsigned short* __restrict__ Qb,
    unsigned short* __restrict__ Kb,
    unsigned short* __restrict__ Vt)
{
    const int z = blockIdx.y;
    const unsigned short* __restrict__ Wz = Wb + (size_t)z * (HS * DIMK);
    const int row0 = blockIdx.x * 64;
    __shared__ unsigned short smem[2 * 64 * 64 + 2 * 128 * 64];
    unsigned short* Xs0 = smem;
    unsigned short* Ws0 = smem + 2 * 64 * 64;
    const int tid = threadIdx.x;
    const int wv = tid >> 6, lane = tid & 63;
    const int lr = lane & 15, lg = lane >> 4;

    f32x4 acc[4][2] = {};

    auto stage = [&](int buf, int k0) {
        #pragma unroll
        for (int i = 0; i < 2; ++i) {
            int g = wv * 2 + i;
            int r = g * 8 + (lane >> 3);
            int sp = (lane & 7) ^ (r & 7);
            gload16(Xb + (size_t)(row0 + r) * DIMK + k0 + sp * 8,
                    Xs0 + buf * (64 * 64) + g * 8 * 64);
        }
        #pragma unroll
        for (int i = 0; i < 4; ++i) {
            int g = wv * 4 + i;
            int r = g * 8 + (lane >> 3);
            int sp = (lane & 7) ^ (r & 7);
            gload16(Wz + (size_t)r * DIMK + k0 + sp * 8,
                    Ws0 + buf * (128 * 64) + g * 8 * 64);
        }
    };

    stage(0, 0);
    __syncthreads();
    for (int ks = 0; ks < DIMK / 64; ++ks) {
        const int cur = ks & 1;
        if (ks < DIMK / 64 - 1) stage(cur ^ 1, (ks + 1) * 64);
        const unsigned short* Xc = Xs0 + cur * (64 * 64);
        const unsigned short* Wc = Ws0 + cur * (128 * 64);
        bf16x8 af[4][2], bfr[2][2];
        #pragma unroll
        for (int mi = 0; mi < 4; ++mi)
            #pragma unroll
            for (int kk = 0; kk < 2; ++kk)
                af[mi][kk] = *reinterpret_cast<const bf16x8*>(
                    &Xc[(mi * 16 + lr) * 64 + (((kk * 4 + lg) ^ (lr & 7)) * 8)]);
        #pragma unroll
        for (int ni = 0; ni < 2; ++ni)
            #pragma unroll
            for (int kk = 0; kk < 2; ++kk)
                bfr[ni][kk] = *reinterpret_cast<const bf16x8*>(
                    &Wc[(wv * 32 + ni * 16 + lr) * 64 + (((kk * 4 + lg) ^ (lr & 7)) * 8)]);
        #pragma unroll
        for (int kk = 0; kk < 2; ++kk)
            #pragma unroll
            for (int mi = 0; mi < 4; ++mi)
                #pragma unroll
                for (int ni = 0; ni < 2; ++ni)
                    acc[mi][ni] = __builtin_amdgcn_mfma_f32_16x16x32_bf16(
                        af[mi][kk], bfr[ni][kk], acc[mi][ni], 0, 0, 0);
        __syncthreads();
    }

    if (z < 2) {
        unsigned short* O = (z == 0) ? Qb : Kb;
        const float qs = (z == 0) ? 0.045084220027780106f : 1.0f;  // log2(e)/32
        #pragma unroll
        for (int mi = 0; mi < 4; ++mi) {
            int rowb = row0 + mi * 16 + lg * 4;
            #pragma unroll
            for (int ni = 0; ni < 2; ++ni) {
                int col = wv * 32 + ni * 16 + lr;
                #pragma unroll
                for (int r = 0; r < 4; ++r)
                    O[(size_t)(rowb + r) * HS + col] = f2bf(acc[mi][ni][r] * qs);
            }
        }
    } else {
        unsigned short* Cs = smem;      // [64][132]
        #pragma unroll
        for (int mi = 0; mi < 4; ++mi)
            #pragma unroll
            for (int ni = 0; ni < 2; ++ni)
                #pragma unroll
                for (int r = 0; r < 4; ++r)
                    Cs[(mi * 16 + lg * 4 + r) * 132 + wv * 32 + ni * 16 + lr] = f2bf(acc[mi][ni][r]);
        __syncthreads();
        const int b  = row0 >> 12;
        const int n0 = row0 & (N_SEQ - 1);
        #pragma unroll
        for (int i = 0; i < 4; ++i) {
            int idx = tid + i * 256;
            int d = idx >> 3, c8 = idx & 7;
            ushortv8 v;
            #pragma unroll
            for (int j = 0; j < 8; ++j)
                v[j] = Cs[(c8 * 8 + j) * 132 + d];
            *reinterpret_cast<ushortv8*>(Vt + (size_t)b * HS * N_SEQ + (size_t)d * N_SEQ + n0 + c8 * 8) = v;
        }
    }
}

// ---------------- flash attention: counted-vmcnt 3-buffer pipeline ----------------
// grid (128, S), block 256 = 4 waves, 32 q-rows/wave. LDS = 3x(K 8KB + V 8KB) = 48 KB.
// Uneven KV split: split s gets base+(s<rem) tiles of KVB.
__global__ __launch_bounds__(256, 3) void attn_kernel(
    const unsigned short* __restrict__ Qb,
    const unsigned short* __restrict__ Kb,
    const unsigned short* __restrict__ Vt,
    unsigned short* __restrict__ part,   // [512][S][32][128] bf16
    float* __restrict__ plsum,           // [512][S][32]
    int S)
{
    const int qblk  = blockIdx.x;      // [0,128)
    const int split = blockIdx.y;      // [0,S)
    const int tid = threadIdx.x;
    const int wv = tid >> 6, lane = tid & 63;
    const int l31 = lane & 31, h = lane >> 5;
    const int b    = qblk >> 5;
    const int row0 = (qblk & 31) * 128 + wv * 32;

    __shared__ unsigned short Ks[3][KVB * 128];   // [kv][hd], slot16 ^= (kv&7)
    __shared__ unsigned short Vs[3][128 * KVB];   // [d][kv],  slot4  ^= ((d>>1)&3)

    // Q as B-fragment (pre-scaled by log2(e)/32 in proj)
    bf16x8 qf[8];
    {
        const unsigned short* qp = Qb + ((size_t)b * N_SEQ + row0 + l31) * HS + h * 8;
        #pragma unroll
        for (int kk = 0; kk < 8; ++kk)
            qf[kk] = *reinterpret_cast<const bf16x8*>(qp + kk * 16);
    }

    const int base = TT / S, rem = TT % S;
    const int nt = base + (split < rem ? 1 : 0);
    const int kv_begin = (split * base + (split < rem ? split : rem)) * KVB;

    const unsigned short* Kbb = Kb + (size_t)b * N_SEQ * HS;
    const unsigned short* Vbb = Vt + (size_t)b * HS * N_SEQ;

    auto stage = [&](int buf, int kv0) {
        #pragma unroll
        for (int i = 0; i < 2; ++i) {          // K [32][128]
            int g = wv * 2 + i;
            int r = g * 4 + (lane >> 4);
            int sp = (lane & 15) ^ (r & 7);
            gload16(Kbb + (size_t)(kv0 + r) * HS + sp * 8, &Ks[buf][g * 4 * 128]);
        }
        #pragma unroll
        for (int i = 0; i < 2; ++i) {          // V^T [128][32]
            int g = wv * 2 + i;
            int r = g * 16 + (lane >> 2);
            int sp = (lane & 3) ^ ((r >> 1) & 3);
            gload16(Vbb + (size_t)r * N_SEQ + kv0 + sp * 8, &Vs[buf][g * 16 * KVB]);
        }
    };

    f32x16 ctx[4] = {};
    f32x16 lacc = {};
    const ushortv8 ones_u = {0x3F80,0x3F80,0x3F80,0x3F80,0x3F80,0x3F80,0x3F80,0x3F80};
    const bf16x8 onesf = __builtin_bit_cast(bf16x8, ones_u);

    // prologue: 2 tiles in flight (8 loads/wave), never drained below 4 in main loop
    stage(0, kv_begin);
    stage(1, kv_begin + KVB);
    int cur = 0, nxt = 2;
    for (int t = 0; t < nt; ++t) {
        if (t + 2 < nt) {
            asm volatile("s_waitcnt vmcnt(4)\n\ts_barrier" ::: "memory");
            stage(nxt, kv_begin + (t + 2) * KVB);
        } else if (t + 1 < nt) {
            asm volatile("s_waitcnt vmcnt(4)\n\ts_barrier" ::: "memory");
        } else {
            asm volatile("s_waitcnt vmcnt(0)\n\ts_barrier" ::: "memory");
        }

        // S^T = K Q^T (swapped): lane holds S^T[kv(r,h)][q=l31]
        f32x16 st = {};
        __builtin_amdgcn_s_setprio(1);
        #pragma unroll
        for (int kk = 0; kk < 8; ++kk) {
            bf16x8 kf = *reinterpret_cast<const bf16x8*>(
                &Ks[cur][l31 * 128 + (((kk * 2 + h) ^ (l31 & 7)) * 8)]);
            st = __builtin_amdgcn_mfma_f32_32x32x16_bf16(kf, qf[kk], st, 0, 0, 0);
        }
        __builtin_amdgcn_s_setprio(0);

        // P = exp2(S) in registers (Q pre-scaled); repack via cvt_pk + permlane32_swap
        float p[16];
        #pragma unroll
        for (int r = 0; r < 16; ++r)
            p[r] = __builtin_amdgcn_exp2f(st[r]);

        bf16x8 pf[2];
        #pragma unroll
        for (int half = 0; half < 2; ++half) {
            unsigned a  = cvtpk(p[half*8 + 0], p[half*8 + 1]);
            unsigned bq = cvtpk(p[half*8 + 2], p[half*8 + 3]);
            unsigned c  = cvtpk(p[half*8 + 4], p[half*8 + 5]);
            unsigned d  = cvtpk(p[half*8 + 6], p[half*8 + 7]);
            asm("v_permlane32_swap_b32 %0, %1" : "+v"(a), "+v"(c));
            asm("v_permlane32_swap_b32 %0, %1" : "+v"(bq), "+v"(d));
            uintv4 w = { a, bq, c, d };
            pf[half] = __builtin_bit_cast(bf16x8, w);
        }

        __builtin_amdgcn_s_setprio(1);
        lacc = __builtin_amdgcn_mfma_f32_32x32x16_bf16(pf[0], onesf, lacc, 0, 0, 0);
        lacc = __builtin_amdgcn_mfma_f32_32x32x16_bf16(pf[1], onesf, lacc, 0, 0, 0);
        #pragma unroll
        for (int dt = 0; dt < 4; ++dt) {
            int d = dt * 32 + l31;
            bf16x8 vf0 = *reinterpret_cast<const bf16x8*>(
                &Vs[cur][d * KVB + (((0 + h) ^ ((d >> 1) & 3)) * 8)]);
            ctx[dt] = __builtin_amdgcn_mfma_f32_32x32x16_bf16(pf[0], vf0, ctx[dt], 0, 0, 0);
            bf16x8 vf1 = *reinterpret_cast<const bf16x8*>(
                &Vs[cur][d * KVB + (((2 + h) ^ ((d >> 1) & 3)) * 8)]);
            ctx[dt] = __builtin_amdgcn_mfma_f32_32x32x16_bf16(pf[1], vf1, ctx[dt], 0, 0, 0);
        }
        __builtin_amdgcn_s_setprio(0);

        cur = (cur == 2) ? 0 : cur + 1;
        nxt = (nxt == 2) ? 0 : nxt + 1;
    }

    // ---- write bf16 partials ----
    const int qt = qblk * 4 + wv;              // [0,512) 32-row tile
    unsigned short* pp = part + ((size_t)qt * S + split) * (32 * 128);
    #pragma unroll
    for (int rp = 0; rp < 4; ++rp)
        #pragma unroll
        for (int rq = 0; rq < 4; ++rq) {
            const int r = rp * 4 + rq;
            const int q = rq + 8 * rp + 4 * h;
            #pragma unroll
            for (int dt = 0; dt < 4; ++dt)
                pp[q * 128 + dt * 32 + l31] = (unsigned short)(cvtpk(ctx[dt][r], ctx[dt][r]) & 0xFFFFu);
        }
    if (l31 == 0) {
        float* pl = plsum + ((size_t)qt * S + split) * 32;
        #pragma unroll
        for (int rp = 0; rp < 4; ++rp)
            #pragma unroll
            for (int rq = 0; rq < 4; ++rq)
                pl[rq + 8 * rp + 4 * h] = lacc[rp * 4 + rq];
    }
}

// combine KV-split partials: out = (sum_s part_s) / (sum_s lsum_s)
__global__ __launch_bounds__(256) void reduce_kernel(
    const unsigned short* __restrict__ part,
    const float* __restrict__ plsum,
    float* __restrict__ out, int S)
{
    const int id = blockIdx.x * 256 + threadIdx.x;   // [0, 16384*128/4)
    const int d4 = (id & 31) * 4;
    const int grow = id >> 5;                        // global q row
    const int qt = grow >> 5, q = grow & 31;
    f32x4 c = {0.f, 0.f, 0.f, 0.f};
    float l = 0.f;
    for (int s = 0; s < S; ++s) {
        ushortv4 pv = *reinterpret_cast<const ushortv4*>(
            &part[(((size_t)qt * S + s) * 32 + q) * 128 + d4]);
        #pragma unroll
        for (int j = 0; j < 4; ++j)
            c[j] += __builtin_bit_cast(float, (unsigned)pv[j] << 16);
        l += plsum[((size_t)qt * S + s) * 32 + q];
    }
    float inv = 1.0f / l;
    f32x4 o = { c[0]*inv, c[1]*inv, c[2]*inv, c[3]*inv };
    *reinterpret_cast<f32x4*>(&out[(size_t)grow * 128 + d4]) = o;
}

extern "C" void kernel_launch(void* const* d_in, const int* in_sizes, int n_in,
                              void* d_out, int out_size, void* d_ws, size_t ws_size,
                              hipStream_t stream) {
    const float* x  = (const float*)d_in[0];
    const float* wq = (const float*)d_in[1];
    const float* wk = (const float*)d_in[2];
    const float* wv = (const float*)d_in[3];

    // ws layout: Xb | Wb | Qb | Kb | Vt | plsum(max 8 splits) ; bf16 part aliases Xb
    unsigned short* Xb = (unsigned short*)d_ws;                 // 33.55 MB
    unsigned short* Wb = Xb + (size_t)ROWS * DIMK;
    unsigned short* Qb = Wb + (size_t)3 * HS * DIMK;
    unsigned short* Kb = Qb + (size_t)ROWS * HS;
    unsigned short* Vt = Kb + (size_t)ROWS * HS;
    float* plsum = (float*)(Vt + (size_t)N_B * HS * N_SEQ);
    unsigned short* part = (unsigned short*)d_ws;               // S*4.19MB <= 33.55MB for S<=8

    const size_t base = ((size_t)ROWS * DIMK + 3 * HS * DIMK + 3 * (size_t)ROWS * HS) * 2;
    int S;
    if      (ws_size >= base + 6 * (size_t)512 * 32 * 4) S = 6;
    else if (ws_size >= base + 4 * (size_t)512 * 32 * 4) S = 4;
    else if (ws_size >= base + 2 * (size_t)512 * 32 * 4) S = 2;
    else                                                 S = 1;

    cast_kernel<<<8192 + 192, 256, 0, stream>>>(x, wq, wk, wv, Xb, Wb);
    proj_kernel<<<dim3(256, 3), 256, 0, stream>>>(Xb, Wb, Qb, Kb, Vt);
    attn_kernel<<<dim3(128, S), 256, 0, stream>>>(Qb, Kb, Vt, part, plsum, S);
    reduce_kernel<<<(ROWS * HS) / 1024, 256, 0, stream>>>(part, plsum, (float*)d_out, S);
}

// Round 7
// 82.351 us; speedup vs baseline: 4.0880x; 1.0149x over previous
//
#include <hip/hip_runtime.h>

using bf16x8   = __attribute__((ext_vector_type(8))) __bf16;
using f32x4    = __attribute__((ext_vector_type(4))) float;
using f32x16   = __attribute__((ext_vector_type(16))) float;
using floatv4  = __attribute__((ext_vector_type(4))) float;
using ushortv4 = __attribute__((ext_vector_type(4))) unsigned short;
using ushortv8 = __attribute__((ext_vector_type(8))) unsigned short;
using uintv4   = __attribute__((ext_vector_type(4))) unsigned int;

#define N_SEQ 4096
#define N_B   4
#define DIMK  1024
#define HS    128
#define ROWS  (N_B * N_SEQ)
#define KVB   32
#define TT    (N_SEQ / KVB)   // 128 kv tiles

__device__ __forceinline__ unsigned short f2bf(float f) {
    unsigned u = __builtin_bit_cast(unsigned, f);
    u += 0x7FFFu + ((u >> 16) & 1u);   // RNE
    return (unsigned short)(u >> 16);
}

__device__ __forceinline__ unsigned cvtpk(float lo, float hi) {
    unsigned r;
    asm("v_cvt_pk_bf16_f32 %0, %1, %2" : "=v"(r) : "v"(lo), "v"(hi));
    return r;
}

__device__ __forceinline__ void gload16(const unsigned short* g, unsigned short* l) {
    __builtin_amdgcn_global_load_lds(
        (const __attribute__((address_space(1))) unsigned int*)g,
        (__attribute__((address_space(3))) unsigned int*)l, 16, 0, 0);
}

// ---------------- cast W only: Wq, Wk, Wv -> bf16 (1.5 MB) ----------------
__global__ __launch_bounds__(256) void castw_kernel(
    const float* __restrict__ Wq,
    const float* __restrict__ Wk,
    const float* __restrict__ Wv,
    unsigned short* __restrict__ Wb)
{
    const int blk = blockIdx.x;           // [0,192): 64 blocks per W
    const int z = blk >> 6;
    const float* src = (z == 0) ? Wq : (z == 1) ? Wk : Wv;
    unsigned short* dst = Wb + (size_t)z * (HS * DIMK);
    size_t i = (size_t)(blk & 63) * 2048 + (size_t)threadIdx.x * 8;
    floatv4 a = *reinterpret_cast<const floatv4*>(src + i);
    floatv4 b = *reinterpret_cast<const floatv4*>(src + i + 4);
    ushortv8 o = { f2bf(a.x), f2bf(a.y), f2bf(a.z), f2bf(a.w),
                   f2bf(b.x), f2bf(b.y), f2bf(b.z), f2bf(b.w) };
    *reinterpret_cast<ushortv8*>(dst + i) = o;
}

// ---------------- projection: O = X @ Wz^T, fused X cast, dbuf pipeline ----------------
// grid (256, 3), block 256 = 4 waves. Tile 64 rows x 128 cols, BK=64.
// X: fp32 global -> regs -> cvt_pk -> swizzled ds_write (T14). W: bf16 gload_lds.
__global__ __launch_bounds__(256, 3) void proj_kernel(
    const float* __restrict__ X,
    const unsigned short* __restrict__ Wb,
    unsigned short* __restrict__ Qb,
    unsigned short* __restrict__ Kb,
    unsigned short* __restrict__ Vt)
{
    const int z = blockIdx.y;
    const unsigned short* __restrict__ Wz = Wb + (size_t)z * (HS * DIMK);
    const int row0 = blockIdx.x * 64;
    __shared__ unsigned short smem[2 * 64 * 64 + 2 * 128 * 64];   // Xs[2] | Ws[2]
    unsigned short* Xs0 = smem;
    unsigned short* Ws0 = smem + 2 * 64 * 64;
    const int tid = threadIdx.x;
    const int wv = tid >> 6, lane = tid & 63;
    const int lr = lane & 15, lg = lane >> 4;

    // X staging geometry: thread -> (row, 16-float chunk)
    const int xrow = tid >> 2, xc = (tid & 3) * 16;
    const float* xg = X + (size_t)(row0 + xrow) * DIMK + xc;
    const int xs0 = (tid & 3) * 2;          // first 8-short slot
    floatv4 xr[4];

    f32x4 acc[4][2] = {};

    auto loadX = [&](int k0) {
        #pragma unroll
        for (int i = 0; i < 4; ++i)
            xr[i] = *reinterpret_cast<const floatv4*>(xg + k0 + i * 4);
    };
    auto writeX = [&](int buf) {
        uintv4 w0 = { cvtpk(xr[0].x, xr[0].y), cvtpk(xr[0].z, xr[0].w),
                      cvtpk(xr[1].x, xr[1].y), cvtpk(xr[1].z, xr[1].w) };
        uintv4 w1 = { cvtpk(xr[2].x, xr[2].y), cvtpk(xr[2].z, xr[2].w),
                      cvtpk(xr[3].x, xr[3].y), cvtpk(xr[3].z, xr[3].w) };
        unsigned short* xb = Xs0 + buf * (64 * 64) + xrow * 64;
        *reinterpret_cast<uintv4*>(&xb[((xs0 ^ (xrow & 7)) * 8)]) = w0;
        *reinterpret_cast<uintv4*>(&xb[(((xs0 + 1) ^ (xrow & 7)) * 8)]) = w1;
    };
    auto stageW = [&](int buf, int k0) {
        #pragma unroll
        for (int i = 0; i < 4; ++i) {
            int g = wv * 4 + i;
            int r = g * 8 + (lane >> 3);
            int sp = (lane & 7) ^ (r & 7);
            gload16(Wz + (size_t)r * DIMK + k0 + sp * 8,
                    Ws0 + buf * (128 * 64) + g * 8 * 64);
        }
    };

    loadX(0);
    stageW(0, 0);
    asm volatile("s_waitcnt vmcnt(0)" ::: "memory");
    writeX(0);
    __syncthreads();

    for (int ks = 0; ks < DIMK / 64; ++ks) {
        const int cur = ks & 1;
        const bool more = (ks + 1 < DIMK / 64);
        if (more) { loadX((ks + 1) * 64); stageW(cur ^ 1, (ks + 1) * 64); }

        const unsigned short* Xc = Xs0 + cur * (64 * 64);
        const unsigned short* Wc = Ws0 + cur * (128 * 64);
        bf16x8 af[4][2], bfr[2][2];
        #pragma unroll
        for (int mi = 0; mi < 4; ++mi)
            #pragma unroll
            for (int kk = 0; kk < 2; ++kk)
                af[mi][kk] = *reinterpret_cast<const bf16x8*>(
                    &Xc[(mi * 16 + lr) * 64 + (((kk * 4 + lg) ^ (lr & 7)) * 8)]);
        #pragma unroll
        for (int ni = 0; ni < 2; ++ni)
            #pragma unroll
            for (int kk = 0; kk < 2; ++kk)
                bfr[ni][kk] = *reinterpret_cast<const bf16x8*>(
                    &Wc[(wv * 32 + ni * 16 + lr) * 64 + (((kk * 4 + lg) ^ (lr & 7)) * 8)]);
        #pragma unroll
        for (int kk = 0; kk < 2; ++kk)
            #pragma unroll
            for (int mi = 0; mi < 4; ++mi)
                #pragma unroll
                for (int ni = 0; ni < 2; ++ni)
                    acc[mi][ni] = __builtin_amdgcn_mfma_f32_16x16x32_bf16(
                        af[mi][kk], bfr[ni][kk], acc[mi][ni], 0, 0, 0);

        if (more) {
            asm volatile("s_waitcnt vmcnt(0)" ::: "memory");   // xr + W-LDS arrived
            writeX(cur ^ 1);
        }
        __syncthreads();
    }

    if (z < 2) {
        unsigned short* O = (z == 0) ? Qb : Kb;
        const float qs = (z == 0) ? 0.045084220027780106f : 1.0f;  // log2(e)/32
        #pragma unroll
        for (int mi = 0; mi < 4; ++mi) {
            int rowb = row0 + mi * 16 + lg * 4;
            #pragma unroll
            for (int ni = 0; ni < 2; ++ni) {
                int col = wv * 32 + ni * 16 + lr;
                #pragma unroll
                for (int r = 0; r < 4; ++r)
                    O[(size_t)(rowb + r) * HS + col] = f2bf(acc[mi][ni][r] * qs);
            }
        }
    } else {
        unsigned short* Cs = smem;      // [64][132]
        #pragma unroll
        for (int mi = 0; mi < 4; ++mi)
            #pragma unroll
            for (int ni = 0; ni < 2; ++ni)
                #pragma unroll
                for (int r = 0; r < 4; ++r)
                    Cs[(mi * 16 + lg * 4 + r) * 132 + wv * 32 + ni * 16 + lr] = f2bf(acc[mi][ni][r]);
        __syncthreads();
        const int b  = row0 >> 12;
        const int n0 = row0 & (N_SEQ - 1);
        #pragma unroll
        for (int i = 0; i < 4; ++i) {
            int idx = tid + i * 256;
            int d = idx >> 3, c8 = idx & 7;
            ushortv8 v;
            #pragma unroll
            for (int j = 0; j < 8; ++j)
                v[j] = Cs[(c8 * 8 + j) * 132 + d];
            *reinterpret_cast<ushortv8*>(Vt + (size_t)b * HS * N_SEQ + (size_t)d * N_SEQ + n0 + c8 * 8) = v;
        }
    }
}

// ---------------- flash attention: counted-vmcnt 3-buffer, split-st, VALU lsum ----------------
// grid (128, S), block 256 = 4 waves, 32 q-rows/wave. LDS = 3x(K 8KB + V 8KB) = 48 KB.
__global__ __launch_bounds__(256, 3) void attn_kernel(
    const unsigned short* __restrict__ Qb,
    const unsigned short* __restrict__ Kb,
    const unsigned short* __restrict__ Vt,
    unsigned short* __restrict__ part,   // [512][S][32][128] bf16
    float* __restrict__ plsum,           // [512][S][32]
    int S)
{
    const int qblk  = blockIdx.x;      // [0,128)
    const int split = blockIdx.y;      // [0,S)
    const int tid = threadIdx.x;
    const int wv = tid >> 6, lane = tid & 63;
    const int l31 = lane & 31, h = lane >> 5;
    const int b    = qblk >> 5;
    const int row0 = (qblk & 31) * 128 + wv * 32;

    __shared__ unsigned short Ks[3][KVB * 128];   // [kv][hd], slot16 ^= (kv&7)
    __shared__ unsigned short Vs[3][128 * KVB];   // [d][kv],  slot4  ^= ((d>>1)&3)

    // Q as B-fragment (pre-scaled by log2(e)/32 in proj)
    bf16x8 qf[8];
    {
        const unsigned short* qp = Qb + ((size_t)b * N_SEQ + row0 + l31) * HS + h * 8;
        #pragma unroll
        for (int kk = 0; kk < 8; ++kk)
            qf[kk] = *reinterpret_cast<const bf16x8*>(qp + kk * 16);
    }

    const int base = TT / S, rem = TT % S;
    const int nt = base + (split < rem ? 1 : 0);
    const int kv_begin = (split * base + (split < rem ? split : rem)) * KVB;

    const unsigned short* Kbb = Kb + (size_t)b * N_SEQ * HS;
    const unsigned short* Vbb = Vt + (size_t)b * HS * N_SEQ;

    auto stage = [&](int buf, int kv0) {
        #pragma unroll
        for (int i = 0; i < 2; ++i) {          // K [32][128]
            int g = wv * 2 + i;
            int r = g * 4 + (lane >> 4);
            int sp = (lane & 15) ^ (r & 7);
            gload16(Kbb + (size_t)(kv0 + r) * HS + sp * 8, &Ks[buf][g * 4 * 128]);
        }
        #pragma unroll
        for (int i = 0; i < 2; ++i) {          // V^T [128][32]
            int g = wv * 2 + i;
            int r = g * 16 + (lane >> 2);
            int sp = (lane & 3) ^ ((r >> 1) & 3);
            gload16(Vbb + (size_t)r * N_SEQ + kv0 + sp * 8, &Vs[buf][g * 16 * KVB]);
        }
    };

    f32x16 ctx[4] = {};
    float lsum = 0.f;

    // prologue: 2 tiles in flight, vmcnt never drained below 4 in main loop
    stage(0, kv_begin);
    stage(1, kv_begin + KVB);
    int cur = 0, nxt = 2;
    for (int t = 0; t < nt; ++t) {
        if (t + 2 < nt) {
            asm volatile("s_waitcnt vmcnt(4)\n\ts_barrier" ::: "memory");
            stage(nxt, kv_begin + (t + 2) * KVB);
        } else if (t + 1 < nt) {
            asm volatile("s_waitcnt vmcnt(4)\n\ts_barrier" ::: "memory");
        } else {
            asm volatile("s_waitcnt vmcnt(0)\n\ts_barrier" ::: "memory");
        }

        // S^T = K Q^T (swapped), two independent accumulator chains
        f32x16 st0 = {}, st1 = {};
        __builtin_amdgcn_s_setprio(1);
        #pragma unroll
        for (int kk = 0; kk < 8; kk += 2) {
            bf16x8 kf0 = *reinterpret_cast<const bf16x8*>(
                &Ks[cur][l31 * 128 + (((kk * 2 + h) ^ (l31 & 7)) * 8)]);
            st0 = __builtin_amdgcn_mfma_f32_32x32x16_bf16(kf0, qf[kk], st0, 0, 0, 0);
            bf16x8 kf1 = *reinterpret_cast<const bf16x8*>(
                &Ks[cur][l31 * 128 + ((((kk + 1) * 2 + h) ^ (l31 & 7)) * 8)]);
            st1 = __builtin_amdgcn_mfma_f32_32x32x16_bf16(kf1, qf[kk + 1], st1, 0, 0, 0);
        }
        __builtin_amdgcn_s_setprio(0);

        // P = exp2(st0+st1) in registers (Q pre-scaled)
        float p[16];
        #pragma unroll
        for (int r = 0; r < 16; ++r)
            p[r] = __builtin_amdgcn_exp2f(st0[r] + st1[r]);

        // lsum: per-lane row-sum tree (q = l31 is lane-local)
        {
            float a0 = (p[0] + p[1])   + (p[2] + p[3]);
            float a1 = (p[4] + p[5])   + (p[6] + p[7]);
            float a2 = (p[8] + p[9])   + (p[10] + p[11]);
            float a3 = (p[12] + p[13]) + (p[14] + p[15]);
            lsum += (a0 + a1) + (a2 + a3);
        }

        // repack to PV A-fragments via cvt_pk + permlane32_swap
        bf16x8 pf[2];
        #pragma unroll
        for (int half = 0; half < 2; ++half) {
            unsigned a  = cvtpk(p[half*8 + 0], p[half*8 + 1]);
            unsigned bq = cvtpk(p[half*8 + 2], p[half*8 + 3]);
            unsigned c  = cvtpk(p[half*8 + 4], p[half*8 + 5]);
            unsigned d  = cvtpk(p[half*8 + 6], p[half*8 + 7]);
            asm("v_permlane32_swap_b32 %0, %1" : "+v"(a), "+v"(c));
            asm("v_permlane32_swap_b32 %0, %1" : "+v"(bq), "+v"(d));
            uintv4 w = { a, bq, c, d };
            pf[half] = __builtin_bit_cast(bf16x8, w);
        }

        __builtin_amdgcn_s_setprio(1);
        #pragma unroll
        for (int dt = 0; dt < 4; ++dt) {
            int d = dt * 32 + l31;
            bf16x8 vf0 = *reinterpret_cast<const bf16x8*>(
                &Vs[cur][d * KVB + (((0 + h) ^ ((d >> 1) & 3)) * 8)]);
            ctx[dt] = __builtin_amdgcn_mfma_f32_32x32x16_bf16(pf[0], vf0, ctx[dt], 0, 0, 0);
            bf16x8 vf1 = *reinterpret_cast<const bf16x8*>(
                &Vs[cur][d * KVB + (((2 + h) ^ ((d >> 1) & 3)) * 8)]);
            ctx[dt] = __builtin_amdgcn_mfma_f32_32x32x16_bf16(pf[1], vf1, ctx[dt], 0, 0, 0);
        }
        __builtin_amdgcn_s_setprio(0);

        cur = (cur == 2) ? 0 : cur + 1;
        nxt = (nxt == 2) ? 0 : nxt + 1;
    }

    // cross-half lsum combine: lanes l and l+32 hold the two kv halves of q=l31
    lsum += __shfl_xor(lsum, 32);

    // ---- write bf16 partials ----
    const int qt = qblk * 4 + wv;              // [0,512) 32-row tile
    unsigned short* pp = part + ((size_t)qt * S + split) * (32 * 128);
    #pragma unroll
    for (int rp = 0; rp < 4; ++rp)
        #pragma unroll
        for (int rq = 0; rq < 4; ++rq) {
            const int r = rp * 4 + rq;
            const int q = rq + 8 * rp + 4 * h;
            #pragma unroll
            for (int dt = 0; dt < 4; ++dt)
                pp[q * 128 + dt * 32 + l31] = (unsigned short)(cvtpk(ctx[dt][r], ctx[dt][r]) & 0xFFFFu);
        }
    if (h == 0)
        plsum[((size_t)qt * S + split) * 32 + l31] = lsum;
}

// combine KV-split partials: out = (sum_s part_s) / (sum_s lsum_s)
__global__ __launch_bounds__(256) void reduce_kernel(
    const unsigned short* __restrict__ part,
    const float* __restrict__ plsum,
    float* __restrict__ out, int S)
{
    const int id = blockIdx.x * 256 + threadIdx.x;   // [0, 16384*128/4)
    const int d4 = (id & 31) * 4;
    const int grow = id >> 5;                        // global q row
    const int qt = grow >> 5, q = grow & 31;
    f32x4 c = {0.f, 0.f, 0.f, 0.f};
    float l = 0.f;
    for (int s = 0; s < S; ++s) {
        ushortv4 pv = *reinterpret_cast<const ushortv4*>(
            &part[(((size_t)qt * S + s) * 32 + q) * 128 + d4]);
        #pragma unroll
        for (int j = 0; j < 4; ++j)
            c[j] += __builtin_bit_cast(float, (unsigned)pv[j] << 16);
        l += plsum[((size_t)qt * S + s) * 32 + q];
    }
    float inv = 1.0f / l;
    f32x4 o = { c[0]*inv, c[1]*inv, c[2]*inv, c[3]*inv };
    *reinterpret_cast<f32x4*>(&out[(size_t)grow * 128 + d4]) = o;
}

extern "C" void kernel_launch(void* const* d_in, const int* in_sizes, int n_in,
                              void* d_out, int out_size, void* d_ws, size_t ws_size,
                              hipStream_t stream) {
    const float* x  = (const float*)d_in[0];
    const float* wq = (const float*)d_in[1];
    const float* wk = (const float*)d_in[2];
    const float* wv = (const float*)d_in[3];

    // ws layout (no Xb anymore): Wb | Qb | Kb | Vt | plsum(max S) | part
    unsigned short* Wb = (unsigned short*)d_ws;                 // 0.79 MB
    unsigned short* Qb = Wb + (size_t)3 * HS * DIMK;
    unsigned short* Kb = Qb + (size_t)ROWS * HS;
    unsigned short* Vt = Kb + (size_t)ROWS * HS;
    float* plsum = (float*)(Vt + (size_t)N_B * HS * N_SEQ);

    const size_t fixed = (size_t)3 * HS * DIMK * 2 + (size_t)3 * ROWS * HS * 2;  // 13.4 MB
    const size_t per_split = (size_t)512 * 32 * 4 + (size_t)512 * 32 * 128 * 2;  // 4.26 MB

    int S;
    if      (ws_size >= fixed + 6 * per_split) S = 6;
    else if (ws_size >= fixed + 4 * per_split) S = 4;
    else if (ws_size >= fixed + 2 * per_split) S = 2;
    else                                       S = 1;

    unsigned short* part = (unsigned short*)(plsum + (size_t)512 * S * 32);

    castw_kernel<<<192, 256, 0, stream>>>(wq, wk, wv, Wb);
    proj_kernel<<<dim3(256, 3), 256, 0, stream>>>(x, Wb, Qb, Kb, Vt);
    attn_kernel<<<dim3(128, S), 256, 0, stream>>>(Qb, Kb, Vt, part, plsum, S);
    reduce_kernel<<<(ROWS * HS) / 1024, 256, 0, stream>>>(part, plsum, (float*)d_out, S);
}